// Round 1
// baseline (1280.175 us; speedup 1.0000x reference)
//
#include <hip/hip_runtime.h>
#include <math.h>

#define D     1024
#define H     256
#define BLOW  2048
#define BTOT  4096
#define NCHUNK 32   // 4096 / 128 column chunks in the NT GEMM

// ---------------- workspace layout (float units) ----------------
static const size_t OFF_ZALL = 0;                 // 4096*1024
static const size_t OFF_ZHAT = 4194304;           // z_hat, later reused as pred_tumor
static const size_t OFF_ZTUM = 8388608;           // z_tumor
static const size_t OFF_C    = 12582912;          // C = z_hat@W0 + z_bar@W1 + 2b0+b1
static const size_t TAIL     = 16777216;
static const size_t OFF_SALL = TAIL;              // 4096
static const size_t OFF_SNORM= TAIL + 4096;       // 4096
static const size_t OFF_EGRP = TAIL + 8192;       // 4096
static const size_t OFF_EALL = TAIL + 12288;      // 4096
static const size_t OFF_ENORM= TAIL + 16384;      // 4096
static const size_t OFF_PLOW = TAIL + 20480;      // 1024 (P_low,P_high,P_norm,P_all contiguous)
static const size_t OFF_PHIGH= TAIL + 21504;
static const size_t OFF_PNORM= TAIL + 22528;
static const size_t OFF_PALL = TAIL + 23552;
static const size_t OFF_ZNV  = TAIL + 24576;      // 1024 z_norm vector
static const size_t OFF_WNORM= TAIL + 25600;      // 1024 z_norm @ W0
static const size_t OFF_BIASC= TAIL + 26624;      // 1024 2*b0+b1
static const size_t OFF_STATS= TAIL + 27648;      // 16
static const size_t OFF_ACC  = TAIL + 27664;      // 16 (0: cos sums, 1: hinge sum, 2: tcl sum)
static const size_t OFF_NZ   = TAIL + 27680;      // 4096 ||z_all_i||
static const size_t OFF_DT   = TAIL + 31776;      // 4096 z_i . pred_tumor_i
static const size_t OFF_G    = TAIL + 35872;      // 4096 z_i . w_norm
static const size_t OFF_DIAG = TAIL + 39968;      // 4096 M[i,i]
static const size_t OFF_PART = TAIL + 44064;      // float2[NCHUNK][4096] = 262144 floats
// total = 17,083,424 floats = 68.3 MB

// ---------------- reduction helpers ----------------
__device__ inline float wave_sum(float v){
#pragma unroll
  for (int o = 32; o > 0; o >>= 1) v += __shfl_xor(v, o);
  return v;
}
__device__ inline float wave_maxf(float v){
#pragma unroll
  for (int o = 32; o > 0; o >>= 1) v = fmaxf(v, __shfl_xor(v, o));
  return v;
}
// block of 256 threads (4 waves). Valid on all threads.
__device__ inline float block_sum(float v, float* sb){
  v = wave_sum(v);
  __syncthreads();
  if ((threadIdx.x & 63) == 0) sb[threadIdx.x >> 6] = v;
  __syncthreads();
  return sb[0] + sb[1] + sb[2] + sb[3];
}
__device__ inline float block_maxf(float v, float* sb){
  v = wave_maxf(v);
  __syncthreads();
  if ((threadIdx.x & 63) == 0) sb[threadIdx.x >> 6] = v;
  __syncthreads();
  return fmaxf(fmaxf(sb[0], sb[1]), fmaxf(sb[2], sb[3]));
}

// ---------------- kernels ----------------
__global__ __launch_bounds__(256) void k_concat(const float* __restrict__ zl,
                                                const float* __restrict__ zh,
                                                float* __restrict__ za){
  int row = blockIdx.x;
  const float4* src = (const float4*)((row < BLOW) ? (zl + (size_t)row * D)
                                                   : (zh + (size_t)(row - BLOW) * D));
  float4* dst = (float4*)(za + (size_t)row * D);
  dst[threadIdx.x] = src[threadIdx.x];
}

__global__ void k_zero(float* p, int n){
  int i = blockIdx.x * 256 + threadIdx.x;
  if (i < n) p[i] = 0.f;
}

// scores: s = tanh(x @ Wa1 + ba1) @ Wa2 + ba2, 8 rows per block
#define SROWS 8
__global__ __launch_bounds__(256) void k_scores(const float* __restrict__ X,
        const float* __restrict__ Wa1, const float* __restrict__ ba1,
        const float* __restrict__ Wa2, const float* __restrict__ ba2,
        float* __restrict__ S){
  __shared__ __align__(16) float xs[SROWS][D];   // 32 KB
  __shared__ float cross[4][SROWS];
  int t = threadIdx.x;
  int r0 = blockIdx.x * SROWS;
  const float4* src = (const float4*)(X + (size_t)r0 * D);
  float4* d4 = (float4*)&xs[0][0];
#pragma unroll
  for (int i = 0; i < SROWS; ++i) d4[i * 256 + t] = src[i * 256 + t];
  __syncthreads();
  float acc[SROWS];
#pragma unroll
  for (int r = 0; r < SROWS; ++r) acc[r] = 0.f;
#pragma unroll 4
  for (int k = 0; k < D; ++k){
    float w = Wa1[(size_t)k * H + t];
#pragma unroll
    for (int r = 0; r < SROWS; ++r) acc[r] = fmaf(xs[r][k], w, acc[r]);
  }
  float b1v = ba1[t], w2 = Wa2[t];
  float vals[SROWS];
#pragma unroll
  for (int r = 0; r < SROWS; ++r) vals[r] = tanhf(acc[r] + b1v) * w2;
#pragma unroll
  for (int o = 32; o > 0; o >>= 1){
#pragma unroll
    for (int r = 0; r < SROWS; ++r) vals[r] += __shfl_xor(vals[r], o);
  }
  if ((t & 63) == 0){
    int w = t >> 6;
#pragma unroll
    for (int r = 0; r < SROWS; ++r) cross[w][r] = vals[r];
  }
  __syncthreads();
  if (t < SROWS) S[r0 + t] = cross[0][t] + cross[1][t] + cross[2][t] + cross[3][t] + ba2[0];
}

// group maxes + exp arrays + sums
__global__ __launch_bounds__(256) void k_stats(const float* __restrict__ s_all,
        const float* __restrict__ s_norm, float* __restrict__ e_grp,
        float* __restrict__ e_all, float* __restrict__ e_norm, float* __restrict__ stats){
  __shared__ float sb[4];
  int t = threadIdx.x;
  float m;
  m = -1e30f; for (int i = t; i < BLOW; i += 256) m = fmaxf(m, s_all[i]);
  float ml = block_maxf(m, sb);
  m = -1e30f; for (int i = t; i < BLOW; i += 256) m = fmaxf(m, s_all[BLOW + i]);
  float mh = block_maxf(m, sb);
  m = -1e30f; for (int i = t; i < BTOT; i += 256) m = fmaxf(m, s_norm[i]);
  float mn = block_maxf(m, sb);
  float ma = fmaxf(ml, mh);
  float a;
  a = 0.f; for (int i = t; i < BLOW; i += 256){ float e = __expf(s_all[i] - ml); e_grp[i] = e; a += e; }
  float tl = block_sum(a, sb);
  a = 0.f; for (int i = t; i < BLOW; i += 256){ float e = __expf(s_all[BLOW + i] - mh); e_grp[BLOW + i] = e; a += e; }
  float th = block_sum(a, sb);
  a = 0.f; for (int i = t; i < BTOT; i += 256){ float e = __expf(s_all[i] - ma); e_all[i] = e; a += e; }
  float ta = block_sum(a, sb);
  a = 0.f; for (int i = t; i < BTOT; i += 256){ float e = __expf(s_norm[i] - mn); e_norm[i] = e; a += e; }
  float tn = block_sum(a, sb);
  if (t == 0){
    stats[0] = ml; stats[1] = tl; stats[2] = mh; stats[3] = th;
    stats[4] = ma; stats[5] = ta; stats[6] = mn; stats[7] = tn;
  }
}

// P_g[col] = sum_rows e_row * x[row][col]; groups: 0 low, 1 high, 2 norm, 3 all
__global__ __launch_bounds__(256) void k_pvec(const float* __restrict__ z_all,
        const float* __restrict__ z_normal, const float* __restrict__ e_grp,
        const float* __restrict__ e_all, const float* __restrict__ e_norm,
        float* __restrict__ P){
  int g = blockIdx.z;
  const float* X; const float* E; float* Pg; int nr;
  if (g == 0){ X = z_all;                     E = e_grp;        Pg = P;        nr = BLOW; }
  else if (g == 1){ X = z_all + (size_t)BLOW * D; E = e_grp + BLOW; Pg = P + 1024; nr = BLOW; }
  else if (g == 2){ X = z_normal;             E = e_norm;       Pg = P + 2048; nr = BTOT; }
  else { X = z_all;                           E = e_all;        Pg = P + 3072; nr = BTOT; }
  int col = blockIdx.x * 256 + threadIdx.x;
  int chunk = nr >> 3;                 // gridDim.y == 8
  int rs = blockIdx.y * chunk;
  float a = 0.f;
  for (int r = rs; r < rs + chunk; ++r) a = fmaf(E[r], X[(size_t)r * D + col], a);
  atomicAdd(&Pg[col], a);
}

__global__ __launch_bounds__(256) void k_smallvec(const float* __restrict__ P_norm,
        const float* __restrict__ stats, const float* __restrict__ b0,
        const float* __restrict__ b1, float* __restrict__ znv, float* __restrict__ biasC){
  int c = blockIdx.x * 256 + threadIdx.x;
  znv[c] = P_norm[c] / stats[7];
  biasC[c] = 2.f * b0[c] + b1[c];
}

// w_norm = znv @ W0  (no bias)
__global__ __launch_bounds__(256) void k_wnorm(const float* __restrict__ znv,
        const float* __restrict__ W0, float* __restrict__ w_norm){
  int col = blockIdx.x * 256 + threadIdx.x;
  int kc = blockIdx.y;                 // 8 chunks of 128
  float a = 0.f;
  for (int k = kc * 128; k < kc * 128 + 128; ++k)
    a = fmaf(znv[k], W0[(size_t)k * D + col], a);
  atomicAdd(&w_norm[col], a);
}

// z_hat / z_tumor rows + cos(z,z_hat), cos(z,z_bar) reductions
__global__ __launch_bounds__(256) void k_zhat(const float* __restrict__ z_all,
        const float* __restrict__ z_bar, const float* __restrict__ e_grp,
        const float* __restrict__ e_all, const float* __restrict__ stats,
        const float* __restrict__ P_low, const float* __restrict__ P_high,
        const float* __restrict__ P_all, float* __restrict__ z_hat,
        float* __restrict__ z_tumor, float* __restrict__ nz_arr, float* __restrict__ accum){
  __shared__ float sb[4];
  int i = blockIdx.x, t = threadIdx.x;
  const float* Pg = (i < BLOW) ? P_low : P_high;
  float Tg = (i < BLOW) ? stats[1] : stats[3];
  float Ta = stats[5];
  float eg = e_grp[i], ea = e_all[i];
  float ig = 1.f / (Tg - eg), ia = 1.f / (Ta - ea);
  size_t base = (size_t)i * D;
  float4 x  = ((const float4*)(z_all + base))[t];
  float4 pg = ((const float4*)Pg)[t];
  float4 pa = ((const float4*)P_all)[t];
  float4 zb = ((const float4*)(z_bar + base))[t];
  float4 zh, zt;
  zh.x = (pg.x - eg * x.x) * ig; zh.y = (pg.y - eg * x.y) * ig;
  zh.z = (pg.z - eg * x.z) * ig; zh.w = (pg.w - eg * x.w) * ig;
  zt.x = (pa.x - ea * x.x) * ia; zt.y = (pa.y - ea * x.y) * ia;
  zt.z = (pa.z - ea * x.z) * ia; zt.w = (pa.w - ea * x.w) * ia;
  ((float4*)(z_hat + base))[t] = zh;
  ((float4*)(z_tumor + base))[t] = zt;
  float nz2 = x.x*x.x + x.y*x.y + x.z*x.z + x.w*x.w;
  float nh2 = zh.x*zh.x + zh.y*zh.y + zh.z*zh.z + zh.w*zh.w;
  float dzh = x.x*zh.x + x.y*zh.y + x.z*zh.z + x.w*zh.w;
  float nb2 = zb.x*zb.x + zb.y*zb.y + zb.z*zb.z + zb.w*zb.w;
  float dzb = x.x*zb.x + x.y*zb.y + x.z*zb.z + x.w*zb.w;
  float s_nz2 = block_sum(nz2, sb);
  float s_nh2 = block_sum(nh2, sb);
  float s_dzh = block_sum(dzh, sb);
  float s_nb2 = block_sum(nb2, sb);
  float s_dzb = block_sum(dzb, sb);
  if (t == 0){
    float nz = sqrtf(s_nz2);
    nz_arr[i] = nz;
    float denA = fmaxf(nz, 1e-8f) * fmaxf(sqrtf(s_nh2), 1e-8f);
    float denB = fmaxf(nz, 1e-8f) * fmaxf(sqrtf(s_nb2), 1e-8f);
    atomicAdd(&accum[0], (1.f - s_dzh / denA) + (1.f - s_dzb / denB));
  }
}

// Out[M,N] = A[M,K] @ W[K,N] (+ Add) (+ bias[col]); 128x128 tile, 8x8 micro, BK=16
__global__ __launch_bounds__(256) void k_gemm_nn(const float* __restrict__ A,
        const float* __restrict__ W, const float* __restrict__ Add,
        const float* __restrict__ bias, float* __restrict__ Out,
        int M, int N, int K){
  __shared__ __align__(16) float As[16][132];
  __shared__ __align__(16) float Ws[16][128];
  int tid = threadIdx.x;
  int tx = tid & 15, ty = tid >> 4;
  int row0 = blockIdx.y * 128, col0 = blockIdx.x * 128;
  int arow = tid >> 2, akg = tid & 3;
  int wrow = tid >> 5, wc = (tid & 31) * 4;
  const float* Ap0 = A + (size_t)(row0 + arow) * K + akg * 4;
  const float* Ap1 = Ap0 + (size_t)64 * K;
  const float* Wp0 = W + (size_t)wrow * N + col0 + wc;
  const float* Wp1 = Wp0 + (size_t)8 * N;
  float4 a0 = *(const float4*)Ap0;
  float4 a1 = *(const float4*)Ap1;
  float4 w0 = *(const float4*)Wp0;
  float4 w1 = *(const float4*)Wp1;
  float acc[8][8];
#pragma unroll
  for (int m = 0; m < 8; ++m)
#pragma unroll
    for (int n = 0; n < 8; ++n) acc[m][n] = 0.f;
  for (int kb = 0; kb < K; kb += 16){
    __syncthreads();
    int k0 = akg * 4;
    As[k0+0][arow] = a0.x; As[k0+1][arow] = a0.y; As[k0+2][arow] = a0.z; As[k0+3][arow] = a0.w;
    As[k0+0][64+arow] = a1.x; As[k0+1][64+arow] = a1.y; As[k0+2][64+arow] = a1.z; As[k0+3][64+arow] = a1.w;
    *(float4*)&Ws[wrow][wc] = w0;
    *(float4*)&Ws[wrow + 8][wc] = w1;
    __syncthreads();
    bool more = (kb + 16) < K;
    float4 na0, na1, nw0, nw1;
    if (more){
      na0 = *(const float4*)(Ap0 + kb + 16);
      na1 = *(const float4*)(Ap1 + kb + 16);
      nw0 = *(const float4*)(Wp0 + (size_t)(kb + 16) * N);
      nw1 = *(const float4*)(Wp1 + (size_t)(kb + 16) * N);
    }
#pragma unroll
    for (int k = 0; k < 16; ++k){
      float ar[8], br[8];
      *(float4*)&ar[0] = *(const float4*)&As[k][ty * 8];
      *(float4*)&ar[4] = *(const float4*)&As[k][ty * 8 + 4];
      *(float4*)&br[0] = *(const float4*)&Ws[k][tx * 8];
      *(float4*)&br[4] = *(const float4*)&Ws[k][tx * 8 + 4];
#pragma unroll
      for (int m = 0; m < 8; ++m)
#pragma unroll
        for (int n = 0; n < 8; ++n) acc[m][n] = fmaf(ar[m], br[n], acc[m][n]);
    }
    if (more){ a0 = na0; a1 = na1; w0 = nw0; w1 = nw1; }
  }
#pragma unroll
  for (int m = 0; m < 8; ++m){
    size_t rb = (size_t)(row0 + ty * 8 + m) * N + col0 + tx * 8;
    float4 o_lo = make_float4(acc[m][0], acc[m][1], acc[m][2], acc[m][3]);
    float4 o_hi = make_float4(acc[m][4], acc[m][5], acc[m][6], acc[m][7]);
    if (Add){
      float4 d0 = *(const float4*)(Add + rb);
      float4 d1 = *(const float4*)(Add + rb + 4);
      o_lo.x += d0.x; o_lo.y += d0.y; o_lo.z += d0.z; o_lo.w += d0.w;
      o_hi.x += d1.x; o_hi.y += d1.y; o_hi.z += d1.z; o_hi.w += d1.w;
    }
    if (bias){
      float4 b0v = *(const float4*)(bias + col0 + tx * 8);
      float4 b1v = *(const float4*)(bias + col0 + tx * 8 + 4);
      o_lo.x += b0v.x; o_lo.y += b0v.y; o_lo.z += b0v.z; o_lo.w += b0v.w;
      o_hi.x += b1v.x; o_hi.y += b1v.y; o_hi.z += b1v.z; o_hi.w += b1v.w;
    }
    *(float4*)(Out + rb) = o_lo;
    *(float4*)(Out + rb + 4) = o_hi;
  }
}

// per-row: dt = z.pt, ||pt||, dpn = z.(C+w), ||C+w||, g = z.w; hinge accumulation
__global__ __launch_bounds__(256) void k_rowred2(const float* __restrict__ z_all,
        const float* __restrict__ PT, const float* __restrict__ C,
        const float* __restrict__ w_norm, const float* __restrict__ nz_arr,
        float* __restrict__ dt_arr, float* __restrict__ g_arr, float* __restrict__ accum){
  __shared__ float sb[4];
  int i = blockIdx.x, t = threadIdx.x;
  size_t base = (size_t)i * D;
  float4 x  = ((const float4*)(z_all + base))[t];
  float4 pt = ((const float4*)(PT + base))[t];
  float4 c  = ((const float4*)(C + base))[t];
  float4 w  = ((const float4*)w_norm)[t];
  float4 pn = make_float4(c.x + w.x, c.y + w.y, c.z + w.z, c.w + w.w);
  float dt   = x.x*pt.x + x.y*pt.y + x.z*pt.z + x.w*pt.w;
  float npt2 = pt.x*pt.x + pt.y*pt.y + pt.z*pt.z + pt.w*pt.w;
  float dpn  = x.x*pn.x + x.y*pn.y + x.z*pn.z + x.w*pn.w;
  float npn2 = pn.x*pn.x + pn.y*pn.y + pn.z*pn.z + pn.w*pn.w;
  float gg   = x.x*w.x + x.y*w.y + x.z*w.z + x.w*w.w;
  float s_dt   = block_sum(dt, sb);
  float s_npt2 = block_sum(npt2, sb);
  float s_dpn  = block_sum(dpn, sb);
  float s_npn2 = block_sum(npn2, sb);
  float s_g    = block_sum(gg, sb);
  if (t == 0){
    dt_arr[i] = s_dt; g_arr[i] = s_g;
    float nz = fmaxf(nz_arr[i], 1e-8f);
    float ct = s_dt  / (nz * fmaxf(sqrtf(s_npt2), 1e-8f));
    float cn = s_dpn / (nz * fmaxf(sqrtf(s_npn2), 1e-8f));
    atomicAdd(&accum[1], fmaxf(0.f, 1.f - (ct - cn)));
  }
}

// M = z_all @ C^T with fused per-tile row-(max,sumexp) partials; also saves diag(M)
__global__ __launch_bounds__(256) void k_gemm_nt_lse(const float* __restrict__ A,
        const float* __restrict__ Bm, float2* __restrict__ partials,
        float* __restrict__ diagM){
  __shared__ __align__(16) float As[16][132];
  __shared__ __align__(16) float Bs[16][132];
  int tid = threadIdx.x;
  int tx = tid & 15, ty = tid >> 4;
  int row0 = blockIdx.y * 128, col0 = blockIdx.x * 128;
  int arow = tid >> 2, akg = tid & 3;
  const float* Ap0 = A + (size_t)(row0 + arow) * D + akg * 4;
  const float* Ap1 = Ap0 + (size_t)64 * D;
  const float* Bp0 = Bm + (size_t)(col0 + arow) * D + akg * 4;
  const float* Bp1 = Bp0 + (size_t)64 * D;
  float4 a0 = *(const float4*)Ap0;
  float4 a1 = *(const float4*)Ap1;
  float4 b0 = *(const float4*)Bp0;
  float4 b1 = *(const float4*)Bp1;
  float acc[8][8];
#pragma unroll
  for (int m = 0; m < 8; ++m)
#pragma unroll
    for (int n = 0; n < 8; ++n) acc[m][n] = 0.f;
  for (int kb = 0; kb < 1024; kb += 16){
    __syncthreads();
    int k0 = akg * 4;
    As[k0+0][arow] = a0.x; As[k0+1][arow] = a0.y; As[k0+2][arow] = a0.z; As[k0+3][arow] = a0.w;
    As[k0+0][64+arow] = a1.x; As[k0+1][64+arow] = a1.y; As[k0+2][64+arow] = a1.z; As[k0+3][64+arow] = a1.w;
    Bs[k0+0][arow] = b0.x; Bs[k0+1][arow] = b0.y; Bs[k0+2][arow] = b0.z; Bs[k0+3][arow] = b0.w;
    Bs[k0+0][64+arow] = b1.x; Bs[k0+1][64+arow] = b1.y; Bs[k0+2][64+arow] = b1.z; Bs[k0+3][64+arow] = b1.w;
    __syncthreads();
    bool more = (kb + 16) < 1024;
    float4 na0, na1, nb0, nb1;
    if (more){
      na0 = *(const float4*)(Ap0 + kb + 16);
      na1 = *(const float4*)(Ap1 + kb + 16);
      nb0 = *(const float4*)(Bp0 + kb + 16);
      nb1 = *(const float4*)(Bp1 + kb + 16);
    }
#pragma unroll
    for (int k = 0; k < 16; ++k){
      float ar[8], br[8];
      *(float4*)&ar[0] = *(const float4*)&As[k][ty * 8];
      *(float4*)&ar[4] = *(const float4*)&As[k][ty * 8 + 4];
      *(float4*)&br[0] = *(const float4*)&Bs[k][tx * 8];
      *(float4*)&br[4] = *(const float4*)&Bs[k][tx * 8 + 4];
#pragma unroll
      for (int m = 0; m < 8; ++m)
#pragma unroll
        for (int n = 0; n < 8; ++n) acc[m][n] = fmaf(ar[m], br[n], acc[m][n]);
    }
    if (more){ a0 = na0; a1 = na1; b0 = nb0; b1 = nb1; }
  }
  // fused per-row (max, sumexp) over this 128-col chunk; lanes sharing a row are
  // the 16 consecutive lanes with equal ty (16-aligned group -> xor shuffles stay inside)
#pragma unroll
  for (int m = 0; m < 8; ++m){
    float lm = acc[m][0];
#pragma unroll
    for (int n = 1; n < 8; ++n) lm = fmaxf(lm, acc[m][n]);
    lm = fmaxf(lm, __shfl_xor(lm, 1));
    lm = fmaxf(lm, __shfl_xor(lm, 2));
    lm = fmaxf(lm, __shfl_xor(lm, 4));
    lm = fmaxf(lm, __shfl_xor(lm, 8));
    float ls = 0.f;
#pragma unroll
    for (int n = 0; n < 8; ++n) ls += __expf(acc[m][n] - lm);
    ls += __shfl_xor(ls, 1);
    ls += __shfl_xor(ls, 2);
    ls += __shfl_xor(ls, 4);
    ls += __shfl_xor(ls, 8);
    if (tx == 0)
      partials[(size_t)blockIdx.x * BTOT + (row0 + ty * 8 + m)] = make_float2(lm, ls);
  }
  if (blockIdx.x == blockIdx.y && tx == ty){
#pragma unroll
    for (int m = 0; m < 8; ++m) diagM[row0 + ty * 8 + m] = acc[m][m];
  }
}

// combine chunk partials into lse per row, swap in the tumor diagonal, sum loss_tcl
__global__ __launch_bounds__(256) void k_combine(const float2* __restrict__ partials,
        const float* __restrict__ diagM, const float* __restrict__ dt,
        const float* __restrict__ g, float* __restrict__ accum){
  __shared__ float sb[4];
  int i = blockIdx.x * 256 + threadIdx.x;
  float m = -1e30f, S = 0.f;
  for (int c = 0; c < NCHUNK; ++c){
    float2 p = partials[(size_t)c * BTOT + i];
    float nm = fmaxf(m, p.x);
    S = S * __expf(m - nm) + p.y * __expf(p.x - nm);
    m = nm;
  }
  float vold = diagM[i];
  float vnew = dt[i] - g[i];
  float nm = fmaxf(m, vnew);
  float S2 = S * __expf(m - nm) - __expf(vold - nm) + __expf(vnew - nm);
  float lse = g[i] + nm + logf(S2);
  float contrib = lse - dt[i];
  float tot = block_sum(contrib, sb);
  if (threadIdx.x == 0) atomicAdd(&accum[2], tot);
}

__global__ void k_final(const float* __restrict__ accum, float* __restrict__ out){
  out[0] = accum[2] / (float)BTOT;
  out[1] = (accum[0] + accum[1]) / (float)BTOT;
}

// ---------------- launch ----------------
extern "C" void kernel_launch(void* const* d_in, const int* in_sizes, int n_in,
                              void* d_out, int out_size, void* d_ws, size_t ws_size,
                              hipStream_t stream){
  const float* z_low    = (const float*)d_in[0];
  const float* z_high   = (const float*)d_in[1];
  const float* z_bar    = (const float*)d_in[2];
  const float* z_normal = (const float*)d_in[3];
  const float* Wa1      = (const float*)d_in[4];
  const float* ba1      = (const float*)d_in[5];
  const float* Wa2      = (const float*)d_in[6];
  const float* ba2      = (const float*)d_in[7];
  const float* W0       = (const float*)d_in[8];
  const float* b0       = (const float*)d_in[9];
  const float* W1       = (const float*)d_in[10];
  const float* b1       = (const float*)d_in[11];
  float* ws = (float*)d_ws;
  float* out = (float*)d_out;

  k_concat<<<dim3(BTOT), dim3(256), 0, stream>>>(z_low, z_high, ws + OFF_ZALL);

  k_scores<<<dim3(BTOT / SROWS), dim3(256), 0, stream>>>(ws + OFF_ZALL, Wa1, ba1, Wa2, ba2, ws + OFF_SALL);
  k_scores<<<dim3(BTOT / SROWS), dim3(256), 0, stream>>>(z_normal, Wa1, ba1, Wa2, ba2, ws + OFF_SNORM);

  k_zero<<<dim3(16), dim3(256), 0, stream>>>(ws + OFF_PLOW, 4096);   // P_low..P_all
  k_zero<<<dim3(4),  dim3(256), 0, stream>>>(ws + OFF_WNORM, 1024);
  k_zero<<<dim3(1),  dim3(256), 0, stream>>>(ws + OFF_ACC, 16);

  k_stats<<<dim3(1), dim3(256), 0, stream>>>(ws + OFF_SALL, ws + OFF_SNORM,
      ws + OFF_EGRP, ws + OFF_EALL, ws + OFF_ENORM, ws + OFF_STATS);

  k_pvec<<<dim3(4, 8, 4), dim3(256), 0, stream>>>(ws + OFF_ZALL, z_normal,
      ws + OFF_EGRP, ws + OFF_EALL, ws + OFF_ENORM, ws + OFF_PLOW);

  k_smallvec<<<dim3(4), dim3(256), 0, stream>>>(ws + OFF_PNORM, ws + OFF_STATS,
      b0, b1, ws + OFF_ZNV, ws + OFF_BIASC);

  k_wnorm<<<dim3(4, 8), dim3(256), 0, stream>>>(ws + OFF_ZNV, W0, ws + OFF_WNORM);

  k_zhat<<<dim3(BTOT), dim3(256), 0, stream>>>(ws + OFF_ZALL, z_bar,
      ws + OFF_EGRP, ws + OFF_EALL, ws + OFF_STATS,
      ws + OFF_PLOW, ws + OFF_PHIGH, ws + OFF_PALL,
      ws + OFF_ZHAT, ws + OFF_ZTUM, ws + OFF_NZ, ws + OFF_ACC);

  // C = z_hat @ W0 + biasC
  k_gemm_nn<<<dim3(8, 32), dim3(256), 0, stream>>>(ws + OFF_ZHAT, W0, nullptr,
      ws + OFF_BIASC, ws + OFF_C, BTOT, D, D);
  // C += z_bar @ W1
  k_gemm_nn<<<dim3(8, 32), dim3(256), 0, stream>>>(z_bar, W1, ws + OFF_C,
      nullptr, ws + OFF_C, BTOT, D, D);
  // PT = z_tumor @ W0 + C   (PT reuses z_hat buffer; z_hat no longer needed)
  k_gemm_nn<<<dim3(8, 32), dim3(256), 0, stream>>>(ws + OFF_ZTUM, W0, ws + OFF_C,
      nullptr, ws + OFF_ZHAT, BTOT, D, D);

  k_rowred2<<<dim3(BTOT), dim3(256), 0, stream>>>(ws + OFF_ZALL, ws + OFF_ZHAT,
      ws + OFF_C, ws + OFF_WNORM, ws + OFF_NZ, ws + OFF_DT, ws + OFF_G, ws + OFF_ACC);

  k_gemm_nt_lse<<<dim3(32, 32), dim3(256), 0, stream>>>(ws + OFF_ZALL, ws + OFF_C,
      (float2*)(ws + OFF_PART), ws + OFF_DIAG);

  k_combine<<<dim3(16), dim3(256), 0, stream>>>((const float2*)(ws + OFF_PART),
      ws + OFF_DIAG, ws + OFF_DT, ws + OFF_G, ws + OFF_ACC);

  k_final<<<dim3(1), dim3(1), 0, stream>>>(ws + OFF_ACC, out);
}

// Round 2
// 649.482 us; speedup vs baseline: 1.9711x; 1.9711x over previous
//
#include <hip/hip_runtime.h>
#include <math.h>

#define D     1024
#define H     256
#define BLOW  2048
#define BTOT  4096
#define NCHUNK 64   // 4096 / 64 col chunks (per-wave) in the NT-LSE GEMM

using bf16x8 = __attribute__((ext_vector_type(8))) __bf16;
using f32x4  = __attribute__((ext_vector_type(4))) float;

// ---------------- workspace layout ----------------
// fp32 region (float units)
static const size_t OFF_ZALL = 0;                 // 4096*1024
static const size_t OFF_C    = 4194304;           // C fp32
static const size_t OFF_PT   = 8388608;           // pred_tumor fp32
static const size_t T0       = 12582912;
static const size_t OFF_SALL = T0;                // 4096
static const size_t OFF_SNORM= T0 + 4096;         // 4096
static const size_t OFF_EGRP = T0 + 8192;         // 4096
static const size_t OFF_EALL = T0 + 12288;        // 4096
static const size_t OFF_ENORM= T0 + 16384;        // 4096
static const size_t OFF_PLOW = T0 + 20480;        // 1024 x4 contiguous
static const size_t OFF_PHIGH= T0 + 21504;
static const size_t OFF_PNORM= T0 + 22528;
static const size_t OFF_PALL = T0 + 23552;
static const size_t OFF_ZNV  = T0 + 24576;        // 1024
static const size_t OFF_WNORM= T0 + 25600;        // 1024
static const size_t OFF_BIASC= T0 + 26624;        // 1024
static const size_t OFF_STATS= T0 + 27648;        // 16
static const size_t OFF_ACC  = T0 + 27664;        // 16
static const size_t OFF_NZ   = T0 + 27680;        // 4096
static const size_t OFF_DT   = T0 + 31776;        // 4096
static const size_t OFF_G    = T0 + 35872;        // 4096
static const size_t OFF_DIAG = T0 + 39968;        // 4096
static const size_t OFF_PART = T0 + 44064;        // float2[64][4096] = 524288 floats
// fp32 end = 13,151,264 floats
static const size_t BF_BASE_F = 13160448;         // bf16 region starts here (float units)
// bf16 offsets (ushort units)
static const size_t BF_ZALL = 0;
static const size_t BF_ZHAT = 4194304;
static const size_t BF_ZTUM = 8388608;
static const size_t BF_ZBAR = 12582912;
static const size_t BF_ZNORM= 16777216;
static const size_t BF_C    = 20971520;
static const size_t BF_W0T  = 25165824;           // 1024x1024
static const size_t BF_W1T  = 26214400;
static const size_t BF_WA1T = 27262976;           // 256x1024
// bf16 end = 27,525,120 ushorts; grand total ~108 MB

// ---------------- helpers ----------------
__device__ inline unsigned short f2bf(float f){
  unsigned u = __float_as_uint(f);
  u += 0x7fffu + ((u >> 16) & 1u);
  return (unsigned short)(u >> 16);
}
__device__ inline float wave_sum(float v){
#pragma unroll
  for (int o = 32; o > 0; o >>= 1) v += __shfl_xor(v, o);
  return v;
}
__device__ inline float wave_maxf(float v){
#pragma unroll
  for (int o = 32; o > 0; o >>= 1) v = fmaxf(v, __shfl_xor(v, o));
  return v;
}
__device__ inline float block_sum(float v, float* sb){
  v = wave_sum(v);
  __syncthreads();
  if ((threadIdx.x & 63) == 0) sb[threadIdx.x >> 6] = v;
  __syncthreads();
  return sb[0] + sb[1] + sb[2] + sb[3];
}
__device__ inline float block_maxf(float v, float* sb){
  v = wave_maxf(v);
  __syncthreads();
  if ((threadIdx.x & 63) == 0) sb[threadIdx.x >> 6] = v;
  __syncthreads();
  return fmaxf(fmaxf(sb[0], sb[1]), fmaxf(sb[2], sb[3]));
}

// ---------------- data prep kernels ----------------
__global__ __launch_bounds__(256) void k_concat(const float* __restrict__ zl,
        const float* __restrict__ zh, float* __restrict__ za, unsigned short* __restrict__ za_bf){
  int row = blockIdx.x, t = threadIdx.x;
  const float4* src = (const float4*)((row < BLOW) ? (zl + (size_t)row * D)
                                                   : (zh + (size_t)(row - BLOW) * D));
  float4 v = src[t];
  ((float4*)(za + (size_t)row * D))[t] = v;
  ushort4 o = make_ushort4(f2bf(v.x), f2bf(v.y), f2bf(v.z), f2bf(v.w));
  *(ushort4*)(za_bf + (size_t)row * D + t * 4) = o;
}

__global__ __launch_bounds__(256) void k_conv(const float* __restrict__ in,
        unsigned short* __restrict__ out){
  int i = blockIdx.x * 256 + threadIdx.x;
  float4 v = ((const float4*)in)[i];
  *(ushort4*)(out + (size_t)i * 4) = make_ushort4(f2bf(v.x), f2bf(v.y), f2bf(v.z), f2bf(v.w));
}

// transpose+convert: in fp32 [R][C] -> out bf16 [C][R]
__global__ __launch_bounds__(256) void k_tconv(const float* __restrict__ in,
        unsigned short* __restrict__ out, int R, int C){
  __shared__ float tile[32][33];
  int t = threadIdx.x;
  int lr = t >> 3;
  int lc = (t & 7) << 2;
  int gr = blockIdx.y * 32, gc = blockIdx.x * 32;
  float4 v = *(const float4*)(in + (size_t)(gr + lr) * C + gc + lc);
  tile[lr][lc + 0] = v.x; tile[lr][lc + 1] = v.y; tile[lr][lc + 2] = v.z; tile[lr][lc + 3] = v.w;
  __syncthreads();
  ushort4 o = make_ushort4(f2bf(tile[lc + 0][lr]), f2bf(tile[lc + 1][lr]),
                           f2bf(tile[lc + 2][lr]), f2bf(tile[lc + 3][lr]));
  *(ushort4*)(out + (size_t)(gc + lr) * R + gr + lc) = o;
}

__global__ void k_zero(float* p, int n){
  int i = blockIdx.x * 256 + threadIdx.x;
  if (i < n) p[i] = 0.f;
}

// ---------------- MFMA core: Out += A[M][1024] . B[N][1024]^T (both bf16, K-contiguous)
// 128x128 tile, 4 waves (2x2), each wave 64x64 = 4x4 frags of 16x16x32.
#define LDK 40   // padded LDS row length in bf16 elems (80 B)
__device__ inline void mfma_core_nt(const unsigned short* __restrict__ A,
                                    const unsigned short* __restrict__ B,
                                    int row0, int col0,
                                    unsigned short* As, unsigned short* Bs,
                                    f32x4 acc[4][4]){
  int t = threadIdx.x;
  int l = t & 63;
  int w = t >> 6;
  int wrow = w >> 1, wcol = w & 1;
  int g = l >> 4, c15 = l & 15;
  int r = t & 127, half = t >> 7;
  const bf16x8* Ap = (const bf16x8*)(A + (size_t)(row0 + r) * 1024 + half * 16);
  const bf16x8* Bp = (const bf16x8*)(B + (size_t)(col0 + r) * 1024 + half * 16);
  bf16x8 a0 = Ap[0], a1 = Ap[1], b0 = Bp[0], b1 = Bp[1];
  f32x4 z = {0.f, 0.f, 0.f, 0.f};
#pragma unroll
  for (int m = 0; m < 4; ++m)
#pragma unroll
    for (int n = 0; n < 4; ++n) acc[m][n] = z;
  int aw = r * LDK + half * 16;
  int rbase = (wrow * 64 + c15) * LDK + 8 * g;
  int cbase = (wcol * 64 + c15) * LDK + 8 * g;
  for (int kb = 0; kb < 1024; kb += 32){
    __syncthreads();
    *(bf16x8*)&As[aw] = a0; *(bf16x8*)&As[aw + 8] = a1;
    *(bf16x8*)&Bs[aw] = b0; *(bf16x8*)&Bs[aw + 8] = b1;
    __syncthreads();
    if (kb + 32 < 1024){
      int o = (kb + 32) >> 3;
      a0 = Ap[o]; a1 = Ap[o + 1]; b0 = Bp[o]; b1 = Bp[o + 1];
    }
    bf16x8 af[4], bfr[4];
#pragma unroll
    for (int m = 0; m < 4; ++m) af[m]  = *(const bf16x8*)&As[rbase + m * 16 * LDK];
#pragma unroll
    for (int n = 0; n < 4; ++n) bfr[n] = *(const bf16x8*)&Bs[cbase + n * 16 * LDK];
#pragma unroll
    for (int m = 0; m < 4; ++m)
#pragma unroll
      for (int n = 0; n < 4; ++n)
        acc[m][n] = __builtin_amdgcn_mfma_f32_16x16x32_bf16(af[m], bfr[n], acc[m][n], 0, 0, 0);
  }
}

// scores GEMM: S[row] += sum_col tanh(z@Wa1 + ba1)[col] * Wa2[col]   (ba2 dropped: softmax-invariant)
__global__ __launch_bounds__(256) void k_scores_bf(const unsigned short* __restrict__ Zbf,
        const unsigned short* __restrict__ Wa1T, const float* __restrict__ ba1,
        const float* __restrict__ Wa2, float* __restrict__ S){
  __shared__ __align__(16) unsigned short smem[2 * 128 * LDK];
  f32x4 acc[4][4];
  int row0 = blockIdx.y * 128, col0 = blockIdx.x * 128;
  mfma_core_nt(Zbf, Wa1T, row0, col0, smem, smem + 128 * LDK, acc);
  int t = threadIdx.x, l = t & 63, w = t >> 6, wrow = w >> 1, wcol = w & 1;
  int g = l >> 4, c15 = l & 15;
#pragma unroll
  for (int m = 0; m < 4; ++m){
#pragma unroll
    for (int r = 0; r < 4; ++r){
      float v = 0.f;
#pragma unroll
      for (int n = 0; n < 4; ++n){
        int col = col0 + wcol * 64 + n * 16 + c15;
        float x = acc[m][n][r] + ba1[col];
        float e = __expf(2.f * x);
        v += (1.f - 2.f / (e + 1.f)) * Wa2[col];
      }
      v += __shfl_xor(v, 1); v += __shfl_xor(v, 2); v += __shfl_xor(v, 4); v += __shfl_xor(v, 8);
      if (c15 == 0) atomicAdd(&S[row0 + wrow * 64 + m * 16 + 4 * g + r], v);
    }
  }
}

// general GEMM: Out = A.B^T (+Add) (+bias); optional bf16 mirror. N fixed = 1024.
__global__ __launch_bounds__(256) void k_gemm_bf(const unsigned short* __restrict__ A,
        const unsigned short* __restrict__ B, const float* __restrict__ Add,
        const float* __restrict__ bias, float* __restrict__ Out,
        unsigned short* __restrict__ OutBf){
  __shared__ __align__(16) unsigned short smem[2 * 128 * LDK];
  f32x4 acc[4][4];
  int row0 = blockIdx.y * 128, col0 = blockIdx.x * 128;
  mfma_core_nt(A, B, row0, col0, smem, smem + 128 * LDK, acc);
  int t = threadIdx.x, l = t & 63, w = t >> 6, wrow = w >> 1, wcol = w & 1;
  int g = l >> 4, c15 = l & 15;
#pragma unroll
  for (int m = 0; m < 4; ++m){
    int row = row0 + wrow * 64 + m * 16 + 4 * g;
#pragma unroll
    for (int n = 0; n < 4; ++n){
      int col = col0 + wcol * 64 + n * 16 + c15;
#pragma unroll
      for (int r = 0; r < 4; ++r){
        float v = acc[m][n][r];
        size_t idx = (size_t)(row + r) * 1024 + col;
        if (Add)  v += Add[idx];
        if (bias) v += bias[col];
        Out[idx] = v;
        if (OutBf) OutBf[idx] = f2bf(v);
      }
    }
  }
}

// NT GEMM M = z_all . C^T with fused per-64col-chunk row (max,sumexp) partials + diag
__global__ __launch_bounds__(256) void k_gemm_lse(const unsigned short* __restrict__ A,
        const unsigned short* __restrict__ B, float2* __restrict__ partials,
        float* __restrict__ diagM){
  __shared__ __align__(16) unsigned short smem[2 * 128 * LDK];
  f32x4 acc[4][4];
  int row0 = blockIdx.y * 128, col0 = blockIdx.x * 128;
  mfma_core_nt(A, B, row0, col0, smem, smem + 128 * LDK, acc);
  int t = threadIdx.x, l = t & 63, w = t >> 6, wrow = w >> 1, wcol = w & 1;
  int g = l >> 4, c15 = l & 15;
  int chunk = blockIdx.x * 2 + wcol;
#pragma unroll
  for (int m = 0; m < 4; ++m){
#pragma unroll
    for (int r = 0; r < 4; ++r){
      float lm = acc[m][0][r];
#pragma unroll
      for (int n = 1; n < 4; ++n) lm = fmaxf(lm, acc[m][n][r]);
      lm = fmaxf(lm, __shfl_xor(lm, 1));
      lm = fmaxf(lm, __shfl_xor(lm, 2));
      lm = fmaxf(lm, __shfl_xor(lm, 4));
      lm = fmaxf(lm, __shfl_xor(lm, 8));
      float ls = 0.f;
#pragma unroll
      for (int n = 0; n < 4; ++n) ls += __expf(acc[m][n][r] - lm);
      ls += __shfl_xor(ls, 1); ls += __shfl_xor(ls, 2); ls += __shfl_xor(ls, 4); ls += __shfl_xor(ls, 8);
      if (c15 == 0)
        partials[(size_t)chunk * BTOT + (row0 + wrow * 64 + m * 16 + 4 * g + r)] = make_float2(lm, ls);
    }
  }
  if (blockIdx.x == blockIdx.y && wrow == wcol && ((c15 >> 2) == g)){
#pragma unroll
    for (int m = 0; m < 4; ++m)
      diagM[row0 + wrow * 64 + m * 16 + c15] = acc[m][m][c15 & 3];
  }
}

// ---------------- softmax stats / pooled vectors ----------------
__global__ __launch_bounds__(256) void k_stats(const float* __restrict__ s_all,
        const float* __restrict__ s_norm, float* __restrict__ e_grp,
        float* __restrict__ e_all, float* __restrict__ e_norm, float* __restrict__ stats){
  __shared__ float sb[4];
  int t = threadIdx.x;
  float m;
  m = -1e30f; for (int i = t; i < BLOW; i += 256) m = fmaxf(m, s_all[i]);
  float ml = block_maxf(m, sb);
  m = -1e30f; for (int i = t; i < BLOW; i += 256) m = fmaxf(m, s_all[BLOW + i]);
  float mh = block_maxf(m, sb);
  m = -1e30f; for (int i = t; i < BTOT; i += 256) m = fmaxf(m, s_norm[i]);
  float mn = block_maxf(m, sb);
  float ma = fmaxf(ml, mh);
  float a;
  a = 0.f; for (int i = t; i < BLOW; i += 256){ float e = __expf(s_all[i] - ml); e_grp[i] = e; a += e; }
  float tl = block_sum(a, sb);
  a = 0.f; for (int i = t; i < BLOW; i += 256){ float e = __expf(s_all[BLOW + i] - mh); e_grp[BLOW + i] = e; a += e; }
  float th = block_sum(a, sb);
  a = 0.f; for (int i = t; i < BTOT; i += 256){ float e = __expf(s_all[i] - ma); e_all[i] = e; a += e; }
  float ta = block_sum(a, sb);
  a = 0.f; for (int i = t; i < BTOT; i += 256){ float e = __expf(s_norm[i] - mn); e_norm[i] = e; a += e; }
  float tn = block_sum(a, sb);
  if (t == 0){
    stats[0] = ml; stats[1] = tl; stats[2] = mh; stats[3] = th;
    stats[4] = ma; stats[5] = ta; stats[6] = mn; stats[7] = tn;
  }
}

__global__ __launch_bounds__(256) void k_pvec(const float* __restrict__ z_all,
        const float* __restrict__ z_normal, const float* __restrict__ e_grp,
        const float* __restrict__ e_all, const float* __restrict__ e_norm,
        float* __restrict__ P){
  int gz = blockIdx.z;
  const float* X; const float* E; float* Pg; int nr;
  if (gz == 0){ X = z_all;                         E = e_grp;        Pg = P;        nr = BLOW; }
  else if (gz == 1){ X = z_all + (size_t)BLOW * D; E = e_grp + BLOW; Pg = P + 1024; nr = BLOW; }
  else if (gz == 2){ X = z_normal;                 E = e_norm;       Pg = P + 2048; nr = BTOT; }
  else { X = z_all;                                E = e_all;        Pg = P + 3072; nr = BTOT; }
  int col = blockIdx.x * 256 + threadIdx.x;
  int chunk = nr >> 3;
  int rs = blockIdx.y * chunk;
  float a = 0.f;
  for (int r = rs; r < rs + chunk; ++r) a = fmaf(E[r], X[(size_t)r * D + col], a);
  atomicAdd(&Pg[col], a);
}

__global__ __launch_bounds__(256) void k_smallvec(const float* __restrict__ P_norm,
        const float* __restrict__ stats, const float* __restrict__ b0,
        const float* __restrict__ b1, float* __restrict__ znv, float* __restrict__ biasC){
  int c = blockIdx.x * 256 + threadIdx.x;
  znv[c] = P_norm[c] / stats[7];
  biasC[c] = 2.f * b0[c] + b1[c];
}

__global__ __launch_bounds__(256) void k_wnorm(const float* __restrict__ znv,
        const float* __restrict__ W0, float* __restrict__ w_norm){
  int col = blockIdx.x * 256 + threadIdx.x;
  int kc = blockIdx.y;
  float a = 0.f;
  for (int k = kc * 128; k < kc * 128 + 128; ++k)
    a = fmaf(znv[k], W0[(size_t)k * D + col], a);
  atomicAdd(&w_norm[col], a);
}

// z_hat / z_tumor rows (bf16 out) + cos(z,z_hat), cos(z,z_bar) reductions
__global__ __launch_bounds__(256) void k_zhat(const float* __restrict__ z_all,
        const float* __restrict__ z_bar, const float* __restrict__ e_grp,
        const float* __restrict__ e_all, const float* __restrict__ stats,
        const float* __restrict__ P_low, const float* __restrict__ P_high,
        const float* __restrict__ P_all, unsigned short* __restrict__ zhat_bf,
        unsigned short* __restrict__ ztum_bf, float* __restrict__ nz_arr,
        float* __restrict__ accum){
  __shared__ float sb[4];
  int i = blockIdx.x, t = threadIdx.x;
  const float* Pg = (i < BLOW) ? P_low : P_high;
  float Tg = (i < BLOW) ? stats[1] : stats[3];
  float Ta = stats[5];
  float eg = e_grp[i], ea = e_all[i];
  float ig = 1.f / (Tg - eg), ia = 1.f / (Ta - ea);
  size_t base = (size_t)i * D;
  float4 x  = ((const float4*)(z_all + base))[t];
  float4 pg = ((const float4*)Pg)[t];
  float4 pa = ((const float4*)P_all)[t];
  float4 zb = ((const float4*)(z_bar + base))[t];
  float4 zh, zt;
  zh.x = (pg.x - eg * x.x) * ig; zh.y = (pg.y - eg * x.y) * ig;
  zh.z = (pg.z - eg * x.z) * ig; zh.w = (pg.w - eg * x.w) * ig;
  zt.x = (pa.x - ea * x.x) * ia; zt.y = (pa.y - ea * x.y) * ia;
  zt.z = (pa.z - ea * x.z) * ia; zt.w = (pa.w - ea * x.w) * ia;
  *(ushort4*)(zhat_bf + base + t * 4) = make_ushort4(f2bf(zh.x), f2bf(zh.y), f2bf(zh.z), f2bf(zh.w));
  *(ushort4*)(ztum_bf + base + t * 4) = make_ushort4(f2bf(zt.x), f2bf(zt.y), f2bf(zt.z), f2bf(zt.w));
  float nz2 = x.x*x.x + x.y*x.y + x.z*x.z + x.w*x.w;
  float nh2 = zh.x*zh.x + zh.y*zh.y + zh.z*zh.z + zh.w*zh.w;
  float dzh = x.x*zh.x + x.y*zh.y + x.z*zh.z + x.w*zh.w;
  float nb2 = zb.x*zb.x + zb.y*zb.y + zb.z*zb.z + zb.w*zb.w;
  float dzb = x.x*zb.x + x.y*zb.y + x.z*zb.z + x.w*zb.w;
  float s_nz2 = block_sum(nz2, sb);
  float s_nh2 = block_sum(nh2, sb);
  float s_dzh = block_sum(dzh, sb);
  float s_nb2 = block_sum(nb2, sb);
  float s_dzb = block_sum(dzb, sb);
  if (t == 0){
    float nz = sqrtf(s_nz2);
    nz_arr[i] = nz;
    float denA = fmaxf(nz, 1e-8f) * fmaxf(sqrtf(s_nh2), 1e-8f);
    float denB = fmaxf(nz, 1e-8f) * fmaxf(sqrtf(s_nb2), 1e-8f);
    atomicAdd(&accum[0], (1.f - s_dzh / denA) + (1.f - s_dzb / denB));
  }
}

// per-row: dt = z.pt, ||pt||, dpn = z.(C+w), ||C+w||, g = z.w; hinge accumulation
__global__ __launch_bounds__(256) void k_rowred2(const float* __restrict__ z_all,
        const float* __restrict__ PT, const float* __restrict__ C,
        const float* __restrict__ w_norm, const float* __restrict__ nz_arr,
        float* __restrict__ dt_arr, float* __restrict__ g_arr, float* __restrict__ accum){
  __shared__ float sb[4];
  int i = blockIdx.x, t = threadIdx.x;
  size_t base = (size_t)i * D;
  float4 x  = ((const float4*)(z_all + base))[t];
  float4 pt = ((const float4*)(PT + base))[t];
  float4 c  = ((const float4*)(C + base))[t];
  float4 wv = ((const float4*)w_norm)[t];
  float4 pn = make_float4(c.x + wv.x, c.y + wv.y, c.z + wv.z, c.w + wv.w);
  float dt   = x.x*pt.x + x.y*pt.y + x.z*pt.z + x.w*pt.w;
  float npt2 = pt.x*pt.x + pt.y*pt.y + pt.z*pt.z + pt.w*pt.w;
  float dpn  = x.x*pn.x + x.y*pn.y + x.z*pn.z + x.w*pn.w;
  float npn2 = pn.x*pn.x + pn.y*pn.y + pn.z*pn.z + pn.w*pn.w;
  float gg   = x.x*wv.x + x.y*wv.y + x.z*wv.z + x.w*wv.w;
  float s_dt   = block_sum(dt, sb);
  float s_npt2 = block_sum(npt2, sb);
  float s_dpn  = block_sum(dpn, sb);
  float s_npn2 = block_sum(npn2, sb);
  float s_g    = block_sum(gg, sb);
  if (t == 0){
    dt_arr[i] = s_dt; g_arr[i] = s_g;
    float nz = fmaxf(nz_arr[i], 1e-8f);
    float ct = s_dt  / (nz * fmaxf(sqrtf(s_npt2), 1e-8f));
    float cn = s_dpn / (nz * fmaxf(sqrtf(s_npn2), 1e-8f));
    atomicAdd(&accum[1], fmaxf(0.f, 1.f - (ct - cn)));
  }
}

__global__ __launch_bounds__(256) void k_combine(const float2* __restrict__ partials,
        const float* __restrict__ diagM, const float* __restrict__ dt,
        const float* __restrict__ g, float* __restrict__ accum){
  __shared__ float sb[4];
  int i = blockIdx.x * 256 + threadIdx.x;
  float m = -1e30f, S = 0.f;
  for (int c = 0; c < NCHUNK; ++c){
    float2 p = partials[(size_t)c * BTOT + i];
    float nm = fmaxf(m, p.x);
    S = S * __expf(m - nm) + p.y * __expf(p.x - nm);
    m = nm;
  }
  float vold = diagM[i];
  float vnew = dt[i] - g[i];
  float nm = fmaxf(m, vnew);
  float S2 = S * __expf(m - nm) - __expf(vold - nm) + __expf(vnew - nm);
  float lse = g[i] + nm + logf(S2);
  float contrib = lse - dt[i];
  float tot = block_sum(contrib, sb);
  if (threadIdx.x == 0) atomicAdd(&accum[2], tot);
}

__global__ void k_final(const float* __restrict__ accum, float* __restrict__ out){
  out[0] = accum[2] / (float)BTOT;
  out[1] = (accum[0] + accum[1]) / (float)BTOT;
}

// ---------------- launch ----------------
extern "C" void kernel_launch(void* const* d_in, const int* in_sizes, int n_in,
                              void* d_out, int out_size, void* d_ws, size_t ws_size,
                              hipStream_t stream){
  const float* z_low    = (const float*)d_in[0];
  const float* z_high   = (const float*)d_in[1];
  const float* z_bar    = (const float*)d_in[2];
  const float* z_normal = (const float*)d_in[3];
  const float* Wa1      = (const float*)d_in[4];
  const float* ba1      = (const float*)d_in[5];
  const float* Wa2      = (const float*)d_in[6];
  const float* ba2      = (const float*)d_in[7];   // dropped: softmax shift-invariant
  const float* W0       = (const float*)d_in[8];
  const float* b0       = (const float*)d_in[9];
  const float* W1       = (const float*)d_in[10];
  const float* b1       = (const float*)d_in[11];
  float* ws = (float*)d_ws;
  unsigned short* bw = (unsigned short*)(ws + BF_BASE_F);
  float* out = (float*)d_out;
  (void)ba2;

  k_concat<<<dim3(BTOT), dim3(256), 0, stream>>>(z_low, z_high, ws + OFF_ZALL, bw + BF_ZALL);
  k_conv<<<dim3(4096), dim3(256), 0, stream>>>(z_bar, bw + BF_ZBAR);
  k_conv<<<dim3(4096), dim3(256), 0, stream>>>(z_normal, bw + BF_ZNORM);
  k_tconv<<<dim3(32, 32), dim3(256), 0, stream>>>(W0, bw + BF_W0T, D, D);
  k_tconv<<<dim3(32, 32), dim3(256), 0, stream>>>(W1, bw + BF_W1T, D, D);
  k_tconv<<<dim3(8, 32), dim3(256), 0, stream>>>(Wa1, bw + BF_WA1T, D, H);

  k_zero<<<dim3(32), dim3(256), 0, stream>>>(ws + OFF_SALL, 8192);   // s_all + s_norm
  k_zero<<<dim3(16), dim3(256), 0, stream>>>(ws + OFF_PLOW, 4096);
  k_zero<<<dim3(4),  dim3(256), 0, stream>>>(ws + OFF_WNORM, 1024);
  k_zero<<<dim3(1),  dim3(256), 0, stream>>>(ws + OFF_ACC, 16);

  k_scores_bf<<<dim3(2, 32), dim3(256), 0, stream>>>(bw + BF_ZALL, bw + BF_WA1T, ba1, Wa2, ws + OFF_SALL);
  k_scores_bf<<<dim3(2, 32), dim3(256), 0, stream>>>(bw + BF_ZNORM, bw + BF_WA1T, ba1, Wa2, ws + OFF_SNORM);

  k_stats<<<dim3(1), dim3(256), 0, stream>>>(ws + OFF_SALL, ws + OFF_SNORM,
      ws + OFF_EGRP, ws + OFF_EALL, ws + OFF_ENORM, ws + OFF_STATS);

  k_pvec<<<dim3(4, 8, 4), dim3(256), 0, stream>>>(ws + OFF_ZALL, z_normal,
      ws + OFF_EGRP, ws + OFF_EALL, ws + OFF_ENORM, ws + OFF_PLOW);

  k_smallvec<<<dim3(4), dim3(256), 0, stream>>>(ws + OFF_PNORM, ws + OFF_STATS,
      b0, b1, ws + OFF_ZNV, ws + OFF_BIASC);

  k_wnorm<<<dim3(4, 8), dim3(256), 0, stream>>>(ws + OFF_ZNV, W0, ws + OFF_WNORM);

  k_zhat<<<dim3(BTOT), dim3(256), 0, stream>>>(ws + OFF_ZALL, z_bar,
      ws + OFF_EGRP, ws + OFF_EALL, ws + OFF_STATS,
      ws + OFF_PLOW, ws + OFF_PHIGH, ws + OFF_PALL,
      bw + BF_ZHAT, bw + BF_ZTUM, ws + OFF_NZ, ws + OFF_ACC);

  // C = z_hat @ W0 + (2 b0 + b1)
  k_gemm_bf<<<dim3(8, 32), dim3(256), 0, stream>>>(bw + BF_ZHAT, bw + BF_W0T,
      nullptr, ws + OFF_BIASC, ws + OFF_C, nullptr);
  // C += z_bar @ W1  (also emit bf16 mirror of final C)
  k_gemm_bf<<<dim3(8, 32), dim3(256), 0, stream>>>(bw + BF_ZBAR, bw + BF_W1T,
      ws + OFF_C, nullptr, ws + OFF_C, bw + BF_C);
  // PT = z_tumor @ W0 + C
  k_gemm_bf<<<dim3(8, 32), dim3(256), 0, stream>>>(bw + BF_ZTUM, bw + BF_W0T,
      ws + OFF_C, nullptr, ws + OFF_PT, nullptr);

  k_rowred2<<<dim3(BTOT), dim3(256), 0, stream>>>(ws + OFF_ZALL, ws + OFF_PT,
      ws + OFF_C, ws + OFF_WNORM, ws + OFF_NZ, ws + OFF_DT, ws + OFF_G, ws + OFF_ACC);

  k_gemm_lse<<<dim3(32, 32), dim3(256), 0, stream>>>(bw + BF_ZALL, bw + BF_C,
      (float2*)(ws + OFF_PART), ws + OFF_DIAG);

  k_combine<<<dim3(16), dim3(256), 0, stream>>>((const float2*)(ws + OFF_PART),
      ws + OFF_DIAG, ws + OFF_DT, ws + OFF_G, ws + OFF_ACC);

  k_final<<<dim3(1), dim3(1), 0, stream>>>(ws + OFF_ACC, out);
}

// Round 3
// 555.494 us; speedup vs baseline: 2.3046x; 1.1692x over previous
//
#include <hip/hip_runtime.h>
#include <math.h>

#define D     1024
#define H     256
#define BLOW  2048
#define BTOT  4096
#define NCHUNK 64   // 4096 / 64 col chunks (per-wave) in the NT-LSE GEMM

using bf16x8 = __attribute__((ext_vector_type(8))) __bf16;
using f32x4  = __attribute__((ext_vector_type(4))) float;

// ---------------- workspace layout ----------------
// fp32 region (float units)
static const size_t OFF_ZALL = 0;                 // 4096*1024
static const size_t OFF_C    = 4194304;           // C fp32
static const size_t OFF_PT   = 8388608;           // pred_tumor fp32
static const size_t T0       = 12582912;
static const size_t OFF_SALL = T0;                // 4096
static const size_t OFF_SNORM= T0 + 4096;         // 4096
static const size_t OFF_EGRP = T0 + 8192;         // 4096
static const size_t OFF_ENORM= T0 + 16384;        // 4096
static const size_t OFF_PLOW = T0 + 20480;        // 1024 x4 contiguous
static const size_t OFF_PHIGH= T0 + 21504;
static const size_t OFF_PNORM= T0 + 22528;
static const size_t OFF_PALL = T0 + 23552;
static const size_t OFF_ZNV  = T0 + 24576;        // 1024
static const size_t OFF_WNORM= T0 + 25600;        // 1024
static const size_t OFF_BIASC= T0 + 26624;        // 1024
static const size_t OFF_STATS= T0 + 27648;        // 16
static const size_t OFF_ACC  = T0 + 27664;        // 16
static const size_t OFF_NZ   = T0 + 27680;        // 4096
static const size_t OFF_DT   = T0 + 31776;        // 4096
static const size_t OFF_G    = T0 + 35872;        // 4096
static const size_t OFF_DIAG = T0 + 39968;        // 4096
static const size_t OFF_PART = T0 + 44064;        // float2[64][4096] = 524288 floats
// fp32 end = 13,151,264 floats
static const size_t BF_BASE_F = 13160448;         // bf16 region starts here (float units)
// bf16 offsets (ushort units)
static const size_t BF_ZALL = 0;
static const size_t BF_ZHAT = 4194304;
static const size_t BF_ZTUM = 8388608;
static const size_t BF_ZBAR = 12582912;
static const size_t BF_ZNORM= 16777216;
static const size_t BF_C    = 20971520;
static const size_t BF_W0T  = 25165824;           // 1024x1024
static const size_t BF_W1T  = 26214400;
static const size_t BF_WA1T = 27262976;           // 256x1024
// bf16 end = 27,525,120 ushorts; grand total ~108 MB

// ---------------- helpers ----------------
__device__ inline unsigned short f2bf(float f){
  unsigned u = __float_as_uint(f);
  u += 0x7fffu + ((u >> 16) & 1u);
  return (unsigned short)(u >> 16);
}
__device__ inline float wave_sum(float v){
#pragma unroll
  for (int o = 32; o > 0; o >>= 1) v += __shfl_xor(v, o);
  return v;
}
__device__ inline float wave_maxf(float v){
#pragma unroll
  for (int o = 32; o > 0; o >>= 1) v = fmaxf(v, __shfl_xor(v, o));
  return v;
}
__device__ inline float block_sum(float v, float* sb){
  v = wave_sum(v);
  __syncthreads();
  if ((threadIdx.x & 63) == 0) sb[threadIdx.x >> 6] = v;
  __syncthreads();
  return sb[0] + sb[1] + sb[2] + sb[3];
}
__device__ inline float block_maxf(float v, float* sb){
  v = wave_maxf(v);
  __syncthreads();
  if ((threadIdx.x & 63) == 0) sb[threadIdx.x >> 6] = v;
  __syncthreads();
  return fmaxf(fmaxf(sb[0], sb[1]), fmaxf(sb[2], sb[3]));
}

// ---------------- data prep kernels ----------------
__global__ __launch_bounds__(256) void k_concat(const float* __restrict__ zl,
        const float* __restrict__ zh, float* __restrict__ za, unsigned short* __restrict__ za_bf){
  int row = blockIdx.x, t = threadIdx.x;
  const float4* src = (const float4*)((row < BLOW) ? (zl + (size_t)row * D)
                                                   : (zh + (size_t)(row - BLOW) * D));
  float4 v = src[t];
  ((float4*)(za + (size_t)row * D))[t] = v;
  ushort4 o = make_ushort4(f2bf(v.x), f2bf(v.y), f2bf(v.z), f2bf(v.w));
  *(ushort4*)(za_bf + (size_t)row * D + t * 4) = o;
}

__global__ __launch_bounds__(256) void k_conv(const float* __restrict__ in,
        unsigned short* __restrict__ out){
  int i = blockIdx.x * 256 + threadIdx.x;
  float4 v = ((const float4*)in)[i];
  *(ushort4*)(out + (size_t)i * 4) = make_ushort4(f2bf(v.x), f2bf(v.y), f2bf(v.z), f2bf(v.w));
}

// transpose+convert: in fp32 [R][C] -> out bf16 [C][R]
__global__ __launch_bounds__(256) void k_tconv(const float* __restrict__ in,
        unsigned short* __restrict__ out, int R, int C){
  __shared__ float tile[32][33];
  int t = threadIdx.x;
  int lr = t >> 3;
  int lc = (t & 7) << 2;
  int gr = blockIdx.y * 32, gc = blockIdx.x * 32;
  float4 v = *(const float4*)(in + (size_t)(gr + lr) * C + gc + lc);
  tile[lr][lc + 0] = v.x; tile[lr][lc + 1] = v.y; tile[lr][lc + 2] = v.z; tile[lr][lc + 3] = v.w;
  __syncthreads();
  ushort4 o = make_ushort4(f2bf(tile[lc + 0][lr]), f2bf(tile[lc + 1][lr]),
                           f2bf(tile[lc + 2][lr]), f2bf(tile[lc + 3][lr]));
  *(ushort4*)(out + (size_t)(gc + lr) * R + gr + lc) = o;
}

__global__ void k_zero(float* p, int n){
  int i = blockIdx.x * 256 + threadIdx.x;
  if (i < n) p[i] = 0.f;
}

// ---------------- MFMA core: Out += A[M][1024] . B[N][1024]^T (both bf16, K-contiguous)
// 128x128 tile, 4 waves (2x2), each wave 64x64 = 4x4 frags of 16x16x32.
#define LDK 40   // padded LDS row length in bf16 elems (80 B)
__device__ inline void mfma_core_nt(const unsigned short* __restrict__ A,
                                    const unsigned short* __restrict__ B,
                                    int row0, int col0,
                                    unsigned short* As, unsigned short* Bs,
                                    f32x4 acc[4][4]){
  int t = threadIdx.x;
  int l = t & 63;
  int w = t >> 6;
  int wrow = w >> 1, wcol = w & 1;
  int g = l >> 4, c15 = l & 15;
  int r = t & 127, half = t >> 7;
  const bf16x8* Ap = (const bf16x8*)(A + (size_t)(row0 + r) * 1024 + half * 16);
  const bf16x8* Bp = (const bf16x8*)(B + (size_t)(col0 + r) * 1024 + half * 16);
  bf16x8 a0 = Ap[0], a1 = Ap[1], b0 = Bp[0], b1 = Bp[1];
  f32x4 z = {0.f, 0.f, 0.f, 0.f};
#pragma unroll
  for (int m = 0; m < 4; ++m)
#pragma unroll
    for (int n = 0; n < 4; ++n) acc[m][n] = z;
  int aw = r * LDK + half * 16;
  int rbase = (wrow * 64 + c15) * LDK + 8 * g;
  int cbase = (wcol * 64 + c15) * LDK + 8 * g;
  for (int kb = 0; kb < 1024; kb += 32){
    __syncthreads();
    *(bf16x8*)&As[aw] = a0; *(bf16x8*)&As[aw + 8] = a1;
    *(bf16x8*)&Bs[aw] = b0; *(bf16x8*)&Bs[aw + 8] = b1;
    __syncthreads();
    if (kb + 32 < 1024){
      int o = (kb + 32) >> 3;
      a0 = Ap[o]; a1 = Ap[o + 1]; b0 = Bp[o]; b1 = Bp[o + 1];
    }
    bf16x8 af[4], bfr[4];
#pragma unroll
    for (int m = 0; m < 4; ++m) af[m]  = *(const bf16x8*)&As[rbase + m * 16 * LDK];
#pragma unroll
    for (int n = 0; n < 4; ++n) bfr[n] = *(const bf16x8*)&Bs[cbase + n * 16 * LDK];
#pragma unroll
    for (int m = 0; m < 4; ++m)
#pragma unroll
      for (int n = 0; n < 4; ++n)
        acc[m][n] = __builtin_amdgcn_mfma_f32_16x16x32_bf16(af[m], bfr[n], acc[m][n], 0, 0, 0);
  }
}

// scores GEMM: S[row] += sum_col tanh(z@Wa1 + ba1)[col] * Wa2[col]   (ba2 dropped: softmax-invariant)
__global__ __launch_bounds__(256) void k_scores_bf(const unsigned short* __restrict__ Zbf,
        const unsigned short* __restrict__ Wa1T, const float* __restrict__ ba1,
        const float* __restrict__ Wa2, float* __restrict__ S){
  __shared__ __align__(16) unsigned short smem[2 * 128 * LDK];
  f32x4 acc[4][4];
  int row0 = blockIdx.y * 128, col0 = blockIdx.x * 128;
  mfma_core_nt(Zbf, Wa1T, row0, col0, smem, smem + 128 * LDK, acc);
  int t = threadIdx.x, l = t & 63, w = t >> 6, wrow = w >> 1, wcol = w & 1;
  int g = l >> 4, c15 = l & 15;
#pragma unroll
  for (int m = 0; m < 4; ++m){
#pragma unroll
    for (int r = 0; r < 4; ++r){
      float v = 0.f;
#pragma unroll
      for (int n = 0; n < 4; ++n){
        int col = col0 + wcol * 64 + n * 16 + c15;
        float x = acc[m][n][r] + ba1[col];
        float e = __expf(2.f * x);
        v += (1.f - 2.f / (e + 1.f)) * Wa2[col];
      }
      v += __shfl_xor(v, 1); v += __shfl_xor(v, 2); v += __shfl_xor(v, 4); v += __shfl_xor(v, 8);
      if (c15 == 0) atomicAdd(&S[row0 + wrow * 64 + m * 16 + 4 * g + r], v);
    }
  }
}

// general GEMM: Out = A.B^T (+Add) (+bias); optional bf16 mirror. N fixed = 1024.
__global__ __launch_bounds__(256) void k_gemm_bf(const unsigned short* __restrict__ A,
        const unsigned short* __restrict__ B, const float* __restrict__ Add,
        const float* __restrict__ bias, float* __restrict__ Out,
        unsigned short* __restrict__ OutBf){
  __shared__ __align__(16) unsigned short smem[2 * 128 * LDK];
  f32x4 acc[4][4];
  int row0 = blockIdx.y * 128, col0 = blockIdx.x * 128;
  mfma_core_nt(A, B, row0, col0, smem, smem + 128 * LDK, acc);
  int t = threadIdx.x, l = t & 63, w = t >> 6, wrow = w >> 1, wcol = w & 1;
  int g = l >> 4, c15 = l & 15;
#pragma unroll
  for (int m = 0; m < 4; ++m){
    int row = row0 + wrow * 64 + m * 16 + 4 * g;
#pragma unroll
    for (int n = 0; n < 4; ++n){
      int col = col0 + wcol * 64 + n * 16 + c15;
#pragma unroll
      for (int r = 0; r < 4; ++r){
        float v = acc[m][n][r];
        size_t idx = (size_t)(row + r) * 1024 + col;
        if (Add)  v += Add[idx];
        if (bias) v += bias[col];
        Out[idx] = v;
        if (OutBf) OutBf[idx] = f2bf(v);
      }
    }
  }
}

// NT GEMM M = z_all . C^T with fused per-64col-chunk row (max,sumexp) partials + diag
__global__ __launch_bounds__(256) void k_gemm_lse(const unsigned short* __restrict__ A,
        const unsigned short* __restrict__ B, float2* __restrict__ partials,
        float* __restrict__ diagM){
  __shared__ __align__(16) unsigned short smem[2 * 128 * LDK];
  f32x4 acc[4][4];
  int row0 = blockIdx.y * 128, col0 = blockIdx.x * 128;
  mfma_core_nt(A, B, row0, col0, smem, smem + 128 * LDK, acc);
  int t = threadIdx.x, l = t & 63, w = t >> 6, wrow = w >> 1, wcol = w & 1;
  int g = l >> 4, c15 = l & 15;
  int chunk = blockIdx.x * 2 + wcol;
#pragma unroll
  for (int m = 0; m < 4; ++m){
#pragma unroll
    for (int r = 0; r < 4; ++r){
      float lm = acc[m][0][r];
#pragma unroll
      for (int n = 1; n < 4; ++n) lm = fmaxf(lm, acc[m][n][r]);
      lm = fmaxf(lm, __shfl_xor(lm, 1));
      lm = fmaxf(lm, __shfl_xor(lm, 2));
      lm = fmaxf(lm, __shfl_xor(lm, 4));
      lm = fmaxf(lm, __shfl_xor(lm, 8));
      float ls = 0.f;
#pragma unroll
      for (int n = 0; n < 4; ++n) ls += __expf(acc[m][n][r] - lm);
      ls += __shfl_xor(ls, 1); ls += __shfl_xor(ls, 2); ls += __shfl_xor(ls, 4); ls += __shfl_xor(ls, 8);
      if (c15 == 0)
        partials[(size_t)chunk * BTOT + (row0 + wrow * 64 + m * 16 + 4 * g + r)] = make_float2(lm, ls);
    }
  }
  if (blockIdx.x == blockIdx.y && wrow == wcol && ((c15 >> 2) == g)){
#pragma unroll
    for (int m = 0; m < 4; ++m)
      diagM[row0 + wrow * 64 + m * 16 + c15] = acc[m][m][c15 & 3];
  }
}

// ---------------- softmax stats / pooled vectors ----------------
// stats: 0 ml, 1 tl, 2 mh, 3 th, 4 ma, 5 ta, 6 mn, 7 tn, 8 sl=exp(ml-ma), 9 sh=exp(mh-ma)
__global__ __launch_bounds__(256) void k_stats(const float* __restrict__ s_all,
        const float* __restrict__ s_norm, float* __restrict__ e_grp,
        float* __restrict__ e_norm, float* __restrict__ stats){
  __shared__ float sb[4];
  int t = threadIdx.x;
  float m;
  m = -1e30f; for (int i = t; i < BLOW; i += 256) m = fmaxf(m, s_all[i]);
  float ml = block_maxf(m, sb);
  m = -1e30f; for (int i = t; i < BLOW; i += 256) m = fmaxf(m, s_all[BLOW + i]);
  float mh = block_maxf(m, sb);
  m = -1e30f; for (int i = t; i < BTOT; i += 256) m = fmaxf(m, s_norm[i]);
  float mn = block_maxf(m, sb);
  float ma = fmaxf(ml, mh);
  float a;
  a = 0.f; for (int i = t; i < BLOW; i += 256){ float e = __expf(s_all[i] - ml); e_grp[i] = e; a += e; }
  float tl = block_sum(a, sb);
  a = 0.f; for (int i = t; i < BLOW; i += 256){ float e = __expf(s_all[BLOW + i] - mh); e_grp[BLOW + i] = e; a += e; }
  float th = block_sum(a, sb);
  a = 0.f; for (int i = t; i < BTOT; i += 256){ float e = __expf(s_norm[i] - mn); e_norm[i] = e; a += e; }
  float tn = block_sum(a, sb);
  if (t == 0){
    float sl = __expf(ml - ma), sh = __expf(mh - ma);
    stats[0] = ml; stats[1] = tl; stats[2] = mh; stats[3] = th;
    stats[4] = ma; stats[5] = tl * sl + th * sh; stats[6] = mn; stats[7] = tn;
    stats[8] = sl; stats[9] = sh;
  }
}

// P_g[col] = sum_rows e_row * x[row][col]; groups: 0 low, 1 high, 2 norm.
// grid (1, 256, 3); 16-row chunks; each thread owns 4 columns (float4).
__global__ __launch_bounds__(256) void k_pvec(const float* __restrict__ z_all,
        const float* __restrict__ z_normal, const float* __restrict__ e_grp,
        const float* __restrict__ e_norm, float* __restrict__ P){
  int gz = blockIdx.z;
  const float* X; const float* E; float* Pg; int nr;
  if (gz == 0){ X = z_all;                         E = e_grp;        Pg = P;        nr = BLOW; }
  else if (gz == 1){ X = z_all + (size_t)BLOW * D; E = e_grp + BLOW; Pg = P + 1024; nr = BLOW; }
  else { X = z_normal;                             E = e_norm;       Pg = P + 2048; nr = BTOT; }
  int r0 = blockIdx.y * 16;
  if (r0 >= nr) return;
  int c4 = threadIdx.x * 4;
  float4 a = make_float4(0.f, 0.f, 0.f, 0.f);
#pragma unroll 4
  for (int r = r0; r < r0 + 16; ++r){
    float e = E[r];
    float4 x = *(const float4*)(X + (size_t)r * D + c4);
    a.x = fmaf(e, x.x, a.x); a.y = fmaf(e, x.y, a.y);
    a.z = fmaf(e, x.z, a.z); a.w = fmaf(e, x.w, a.w);
  }
  atomicAdd(&Pg[c4 + 0], a.x);
  atomicAdd(&Pg[c4 + 1], a.y);
  atomicAdd(&Pg[c4 + 2], a.z);
  atomicAdd(&Pg[c4 + 3], a.w);
}

// P_all = sl*P_low + sh*P_high; znv = P_norm / tn; biasC = 2 b0 + b1
__global__ __launch_bounds__(256) void k_smallvec(const float* __restrict__ P,
        const float* __restrict__ stats, const float* __restrict__ b0,
        const float* __restrict__ b1, float* __restrict__ P_all,
        float* __restrict__ znv, float* __restrict__ biasC){
  int c = blockIdx.x * 256 + threadIdx.x;
  znv[c] = P[2048 + c] / stats[7];
  biasC[c] = 2.f * b0[c] + b1[c];
  P_all[c] = stats[8] * P[c] + stats[9] * P[1024 + c];
}

__global__ __launch_bounds__(256) void k_wnorm(const float* __restrict__ znv,
        const float* __restrict__ W0, float* __restrict__ w_norm){
  int col = blockIdx.x * 256 + threadIdx.x;
  int kc = blockIdx.y;
  float a = 0.f;
  for (int k = kc * 128; k < kc * 128 + 128; ++k)
    a = fmaf(znv[k], W0[(size_t)k * D + col], a);
  atomicAdd(&w_norm[col], a);
}

// z_hat / z_tumor rows (bf16 out) + cos(z,z_hat), cos(z,z_bar) reductions
// e_all[i] derived as e_grp[i] * (i<BLOW ? stats[8] : stats[9])
__global__ __launch_bounds__(256) void k_zhat(const float* __restrict__ z_all,
        const float* __restrict__ z_bar, const float* __restrict__ e_grp,
        const float* __restrict__ stats,
        const float* __restrict__ P_low, const float* __restrict__ P_high,
        const float* __restrict__ P_all, unsigned short* __restrict__ zhat_bf,
        unsigned short* __restrict__ ztum_bf, float* __restrict__ nz_arr,
        float* __restrict__ accum){
  __shared__ float sb[4];
  int i = blockIdx.x, t = threadIdx.x;
  const float* Pg = (i < BLOW) ? P_low : P_high;
  float Tg = (i < BLOW) ? stats[1] : stats[3];
  float Ta = stats[5];
  float eg = e_grp[i];
  float ea = eg * ((i < BLOW) ? stats[8] : stats[9]);
  float ig = 1.f / (Tg - eg), ia = 1.f / (Ta - ea);
  size_t base = (size_t)i * D;
  float4 x  = ((const float4*)(z_all + base))[t];
  float4 pg = ((const float4*)Pg)[t];
  float4 pa = ((const float4*)P_all)[t];
  float4 zb = ((const float4*)(z_bar + base))[t];
  float4 zh, zt;
  zh.x = (pg.x - eg * x.x) * ig; zh.y = (pg.y - eg * x.y) * ig;
  zh.z = (pg.z - eg * x.z) * ig; zh.w = (pg.w - eg * x.w) * ig;
  zt.x = (pa.x - ea * x.x) * ia; zt.y = (pa.y - ea * x.y) * ia;
  zt.z = (pa.z - ea * x.z) * ia; zt.w = (pa.w - ea * x.w) * ia;
  *(ushort4*)(zhat_bf + base + t * 4) = make_ushort4(f2bf(zh.x), f2bf(zh.y), f2bf(zh.z), f2bf(zh.w));
  *(ushort4*)(ztum_bf + base + t * 4) = make_ushort4(f2bf(zt.x), f2bf(zt.y), f2bf(zt.z), f2bf(zt.w));
  float nz2 = x.x*x.x + x.y*x.y + x.z*x.z + x.w*x.w;
  float nh2 = zh.x*zh.x + zh.y*zh.y + zh.z*zh.z + zh.w*zh.w;
  float dzh = x.x*zh.x + x.y*zh.y + x.z*zh.z + x.w*zh.w;
  float nb2 = zb.x*zb.x + zb.y*zb.y + zb.z*zb.z + zb.w*zb.w;
  float dzb = x.x*zb.x + x.y*zb.y + x.z*zb.z + x.w*zb.w;
  float s_nz2 = block_sum(nz2, sb);
  float s_nh2 = block_sum(nh2, sb);
  float s_dzh = block_sum(dzh, sb);
  float s_nb2 = block_sum(nb2, sb);
  float s_dzb = block_sum(dzb, sb);
  if (t == 0){
    float nz = sqrtf(s_nz2);
    nz_arr[i] = nz;
    float denA = fmaxf(nz, 1e-8f) * fmaxf(sqrtf(s_nh2), 1e-8f);
    float denB = fmaxf(nz, 1e-8f) * fmaxf(sqrtf(s_nb2), 1e-8f);
    atomicAdd(&accum[0], (1.f - s_dzh / denA) + (1.f - s_dzb / denB));
  }
}

// per-row: dt = z.pt, ||pt||, dpn = z.(C+w), ||C+w||, g = z.w; hinge accumulation
__global__ __launch_bounds__(256) void k_rowred2(const float* __restrict__ z_all,
        const float* __restrict__ PT, const float* __restrict__ C,
        const float* __restrict__ w_norm, const float* __restrict__ nz_arr,
        float* __restrict__ dt_arr, float* __restrict__ g_arr, float* __restrict__ accum){
  __shared__ float sb[4];
  int i = blockIdx.x, t = threadIdx.x;
  size_t base = (size_t)i * D;
  float4 x  = ((const float4*)(z_all + base))[t];
  float4 pt = ((const float4*)(PT + base))[t];
  float4 c  = ((const float4*)(C + base))[t];
  float4 wv = ((const float4*)w_norm)[t];
  float4 pn = make_float4(c.x + wv.x, c.y + wv.y, c.z + wv.z, c.w + wv.w);
  float dt   = x.x*pt.x + x.y*pt.y + x.z*pt.z + x.w*pt.w;
  float npt2 = pt.x*pt.x + pt.y*pt.y + pt.z*pt.z + pt.w*pt.w;
  float dpn  = x.x*pn.x + x.y*pn.y + x.z*pn.z + x.w*pn.w;
  float npn2 = pn.x*pn.x + pn.y*pn.y + pn.z*pn.z + pn.w*pn.w;
  float gg   = x.x*wv.x + x.y*wv.y + x.z*wv.z + x.w*wv.w;
  float s_dt   = block_sum(dt, sb);
  float s_npt2 = block_sum(npt2, sb);
  float s_dpn  = block_sum(dpn, sb);
  float s_npn2 = block_sum(npn2, sb);
  float s_g    = block_sum(gg, sb);
  if (t == 0){
    dt_arr[i] = s_dt; g_arr[i] = s_g;
    float nz = fmaxf(nz_arr[i], 1e-8f);
    float ct = s_dt  / (nz * fmaxf(sqrtf(s_npt2), 1e-8f));
    float cn = s_dpn / (nz * fmaxf(sqrtf(s_npn2), 1e-8f));
    atomicAdd(&accum[1], fmaxf(0.f, 1.f - (ct - cn)));
  }
}

__global__ __launch_bounds__(256) void k_combine(const float2* __restrict__ partials,
        const float* __restrict__ diagM, const float* __restrict__ dt,
        const float* __restrict__ g, float* __restrict__ accum){
  __shared__ float sb[4];
  int i = blockIdx.x * 256 + threadIdx.x;
  float m = -1e30f, S = 0.f;
  for (int c = 0; c < NCHUNK; ++c){
    float2 p = partials[(size_t)c * BTOT + i];
    float nm = fmaxf(m, p.x);
    S = S * __expf(m - nm) + p.y * __expf(p.x - nm);
    m = nm;
  }
  float vold = diagM[i];
  float vnew = dt[i] - g[i];
  float nm = fmaxf(m, vnew);
  float S2 = S * __expf(m - nm) - __expf(vold - nm) + __expf(vnew - nm);
  float lse = g[i] + nm + logf(S2);
  float contrib = lse - dt[i];
  float tot = block_sum(contrib, sb);
  if (threadIdx.x == 0) atomicAdd(&accum[2], tot);
}

__global__ void k_final(const float* __restrict__ accum, float* __restrict__ out){
  out[0] = accum[2] / (float)BTOT;
  out[1] = (accum[0] + accum[1]) / (float)BTOT;
}

// ---------------- launch ----------------
extern "C" void kernel_launch(void* const* d_in, const int* in_sizes, int n_in,
                              void* d_out, int out_size, void* d_ws, size_t ws_size,
                              hipStream_t stream){
  const float* z_low    = (const float*)d_in[0];
  const float* z_high   = (const float*)d_in[1];
  const float* z_bar    = (const float*)d_in[2];
  const float* z_normal = (const float*)d_in[3];
  const float* Wa1      = (const float*)d_in[4];
  const float* ba1      = (const float*)d_in[5];
  const float* Wa2      = (const float*)d_in[6];
  const float* ba2      = (const float*)d_in[7];   // dropped: softmax shift-invariant
  const float* W0       = (const float*)d_in[8];
  const float* b0       = (const float*)d_in[9];
  const float* W1       = (const float*)d_in[10];
  const float* b1       = (const float*)d_in[11];
  float* ws = (float*)d_ws;
  unsigned short* bw = (unsigned short*)(ws + BF_BASE_F);
  float* out = (float*)d_out;
  (void)ba2;

  k_concat<<<dim3(BTOT), dim3(256), 0, stream>>>(z_low, z_high, ws + OFF_ZALL, bw + BF_ZALL);
  k_conv<<<dim3(4096), dim3(256), 0, stream>>>(z_bar, bw + BF_ZBAR);
  k_conv<<<dim3(4096), dim3(256), 0, stream>>>(z_normal, bw + BF_ZNORM);
  k_tconv<<<dim3(32, 32), dim3(256), 0, stream>>>(W0, bw + BF_W0T, D, D);
  k_tconv<<<dim3(32, 32), dim3(256), 0, stream>>>(W1, bw + BF_W1T, D, D);
  k_tconv<<<dim3(8, 32), dim3(256), 0, stream>>>(Wa1, bw + BF_WA1T, D, H);

  k_zero<<<dim3(32), dim3(256), 0, stream>>>(ws + OFF_SALL, 8192);   // s_all + s_norm
  k_zero<<<dim3(16), dim3(256), 0, stream>>>(ws + OFF_PLOW, 4096);
  k_zero<<<dim3(4),  dim3(256), 0, stream>>>(ws + OFF_WNORM, 1024);
  k_zero<<<dim3(1),  dim3(256), 0, stream>>>(ws + OFF_ACC, 16);

  k_scores_bf<<<dim3(2, 32), dim3(256), 0, stream>>>(bw + BF_ZALL, bw + BF_WA1T, ba1, Wa2, ws + OFF_SALL);
  k_scores_bf<<<dim3(2, 32), dim3(256), 0, stream>>>(bw + BF_ZNORM, bw + BF_WA1T, ba1, Wa2, ws + OFF_SNORM);

  k_stats<<<dim3(1), dim3(256), 0, stream>>>(ws + OFF_SALL, ws + OFF_SNORM,
      ws + OFF_EGRP, ws + OFF_ENORM, ws + OFF_STATS);

  k_pvec<<<dim3(1, 256, 3), dim3(256), 0, stream>>>(ws + OFF_ZALL, z_normal,
      ws + OFF_EGRP, ws + OFF_ENORM, ws + OFF_PLOW);

  k_smallvec<<<dim3(4), dim3(256), 0, stream>>>(ws + OFF_PLOW, ws + OFF_STATS,
      b0, b1, ws + OFF_PALL, ws + OFF_ZNV, ws + OFF_BIASC);

  k_wnorm<<<dim3(4, 8), dim3(256), 0, stream>>>(ws + OFF_ZNV, W0, ws + OFF_WNORM);

  k_zhat<<<dim3(BTOT), dim3(256), 0, stream>>>(ws + OFF_ZALL, z_bar,
      ws + OFF_EGRP, ws + OFF_STATS,
      ws + OFF_PLOW, ws + OFF_PHIGH, ws + OFF_PALL,
      bw + BF_ZHAT, bw + BF_ZTUM, ws + OFF_NZ, ws + OFF_ACC);

  // C = z_hat @ W0 + (2 b0 + b1)
  k_gemm_bf<<<dim3(8, 32), dim3(256), 0, stream>>>(bw + BF_ZHAT, bw + BF_W0T,
      nullptr, ws + OFF_BIASC, ws + OFF_C, nullptr);
  // C += z_bar @ W1  (also emit bf16 mirror of final C)
  k_gemm_bf<<<dim3(8, 32), dim3(256), 0, stream>>>(bw + BF_ZBAR, bw + BF_W1T,
      ws + OFF_C, nullptr, ws + OFF_C, bw + BF_C);
  // PT = z_tumor @ W0 + C
  k_gemm_bf<<<dim3(8, 32), dim3(256), 0, stream>>>(bw + BF_ZTUM, bw + BF_W0T,
      ws + OFF_C, nullptr, ws + OFF_PT, nullptr);

  k_rowred2<<<dim3(BTOT), dim3(256), 0, stream>>>(ws + OFF_ZALL, ws + OFF_PT,
      ws + OFF_C, ws + OFF_WNORM, ws + OFF_NZ, ws + OFF_DT, ws + OFF_G, ws + OFF_ACC);

  k_gemm_lse<<<dim3(32, 32), dim3(256), 0, stream>>>(bw + BF_ZALL, bw + BF_C,
      (float2*)(ws + OFF_PART), ws + OFF_DIAG);

  k_combine<<<dim3(16), dim3(256), 0, stream>>>((const float2*)(ws + OFF_PART),
      ws + OFF_DIAG, ws + OFF_DT, ws + OFF_G, ws + OFF_ACC);

  k_final<<<dim3(1), dim3(1), 0, stream>>>(ws + OFF_ACC, out);
}

// Round 4
// 455.127 us; speedup vs baseline: 2.8128x; 1.2205x over previous
//
#include <hip/hip_runtime.h>
#include <math.h>

#define D     1024
#define H     256
#define BLOW  2048
#define BTOT  4096
#define NCHUNK 64   // 4096 / 64 col chunks (per-wave) in the NT-LSE GEMM

using bf16x8 = __attribute__((ext_vector_type(8))) __bf16;
using f32x4  = __attribute__((ext_vector_type(4))) float;

// ---------------- workspace layout ----------------
// fp32 region (float units)
static const size_t OFF_ZALL = 0;                 // 4096*1024
static const size_t OFF_C    = 4194304;           // C fp32
static const size_t OFF_PT   = 8388608;           // pred_tumor fp32
static const size_t T0       = 12582912;
static const size_t OFF_SALL = T0;                // 4096  (s_norm follows contiguously)
static const size_t OFF_SNORM= T0 + 4096;         // 4096
static const size_t OFF_EGRP = T0 + 8192;         // 4096
static const size_t OFF_ENORM= T0 + 16384;        // 4096
static const size_t OFF_PLOW = T0 + 20480;        // 1024 x4 contiguous
static const size_t OFF_PHIGH= T0 + 21504;
static const size_t OFF_PNORM= T0 + 22528;
static const size_t OFF_PALL = T0 + 23552;
static const size_t OFF_ZNV  = T0 + 24576;        // 1024
static const size_t OFF_WNORM= T0 + 25600;        // 1024
static const size_t OFF_BIASC= T0 + 26624;        // 1024
static const size_t OFF_STATS= T0 + 27648;        // 16
static const size_t OFF_ACC  = T0 + 27664;        // 16
static const size_t OFF_NZ   = T0 + 27680;        // 4096
static const size_t OFF_DT   = T0 + 31776;        // 4096
static const size_t OFF_G    = T0 + 35872;        // 4096
static const size_t OFF_DIAG = T0 + 39968;        // 4096
static const size_t OFF_PART = T0 + 44064;        // float2[64][4096] = 524288 floats
static const size_t BF_BASE_F = 13160448;         // bf16 region starts here (float units)
// bf16 offsets (ushort units)
static const size_t BF_ZALLN= 0;                  // [z_all(4096) ; z_normal(4096)] x 1024
static const size_t BF_ZHAT = 8388608;
static const size_t BF_ZTUM = 12582912;
static const size_t BF_ZBAR = 16777216;
static const size_t BF_C    = 20971520;
static const size_t BF_W0T  = 25165824;           // 1024x1024
static const size_t BF_W1T  = 26214400;
static const size_t BF_WA1T = 27262976;           // 256x1024

// ---------------- helpers ----------------
__device__ inline unsigned short f2bf(float f){
  unsigned u = __float_as_uint(f);
  u += 0x7fffu + ((u >> 16) & 1u);
  return (unsigned short)(u >> 16);
}
__device__ inline float wave_sum(float v){
#pragma unroll
  for (int o = 32; o > 0; o >>= 1) v += __shfl_xor(v, o);
  return v;
}
__device__ inline float wave_maxf(float v){
#pragma unroll
  for (int o = 32; o > 0; o >>= 1) v = fmaxf(v, __shfl_xor(v, o));
  return v;
}
__device__ inline float block_sum(float v, float* sb){
  v = wave_sum(v);
  __syncthreads();
  if ((threadIdx.x & 63) == 0) sb[threadIdx.x >> 6] = v;
  __syncthreads();
  return sb[0] + sb[1] + sb[2] + sb[3];
}
__device__ inline float block_maxf(float v, float* sb){
  v = wave_maxf(v);
  __syncthreads();
  if ((threadIdx.x & 63) == 0) sb[threadIdx.x >> 6] = v;
  __syncthreads();
  return fmaxf(fmaxf(sb[0], sb[1]), fmaxf(sb[2], sb[3]));
}

// async global->LDS, 16 B per lane (dest = wave-uniform base + lane*16)
__device__ inline void gload16(const unsigned short* g, unsigned short* l){
  __builtin_amdgcn_global_load_lds(
      (const __attribute__((address_space(1))) unsigned int*)g,
      (__attribute__((address_space(3))) unsigned int*)l, 16, 0, 0);
}

// ---------------- fused prep: concat+conv / conv z_normal / conv z_bar ----------------
__global__ __launch_bounds__(256) void k_prep(const float* __restrict__ zl,
        const float* __restrict__ zh, const float* __restrict__ znorm,
        const float* __restrict__ zbar, float* __restrict__ za,
        unsigned short* __restrict__ zalln_bf, unsigned short* __restrict__ zbar_bf){
  int row = blockIdx.x, t = threadIdx.x, job = blockIdx.z;
  if (job == 0){
    const float4* src = (const float4*)((row < BLOW) ? (zl + (size_t)row * D)
                                                     : (zh + (size_t)(row - BLOW) * D));
    float4 v = src[t];
    ((float4*)(za + (size_t)row * D))[t] = v;
    *(ushort4*)(zalln_bf + (size_t)row * D + t * 4) =
        make_ushort4(f2bf(v.x), f2bf(v.y), f2bf(v.z), f2bf(v.w));
  } else if (job == 1){
    float4 v = ((const float4*)(znorm + (size_t)row * D))[t];
    *(ushort4*)(zalln_bf + (size_t)(BTOT + row) * D + t * 4) =
        make_ushort4(f2bf(v.x), f2bf(v.y), f2bf(v.z), f2bf(v.w));
  } else {
    float4 v = ((const float4*)(zbar + (size_t)row * D))[t];
    *(ushort4*)(zbar_bf + (size_t)row * D + t * 4) =
        make_ushort4(f2bf(v.x), f2bf(v.y), f2bf(v.z), f2bf(v.w));
  }
}

// transpose+convert all three weights in one launch
__global__ __launch_bounds__(256) void k_tconv3(const float* __restrict__ W0,
        const float* __restrict__ W1, const float* __restrict__ Wa1,
        unsigned short* __restrict__ W0T, unsigned short* __restrict__ W1T,
        unsigned short* __restrict__ Wa1T){
  __shared__ float tile[32][33];
  int z = blockIdx.z;
  const float* in; unsigned short* out; int R, C;
  if (z == 0){ in = W0; out = W0T; R = D; C = D; }
  else if (z == 1){ in = W1; out = W1T; R = D; C = D; }
  else { if (blockIdx.x >= 8) return; in = Wa1; out = Wa1T; R = D; C = H; }
  int t = threadIdx.x;
  int lr = t >> 3;
  int lc = (t & 7) << 2;
  int gr = blockIdx.y * 32, gc = blockIdx.x * 32;
  float4 v = *(const float4*)(in + (size_t)(gr + lr) * C + gc + lc);
  tile[lr][lc + 0] = v.x; tile[lr][lc + 1] = v.y; tile[lr][lc + 2] = v.z; tile[lr][lc + 3] = v.w;
  __syncthreads();
  ushort4 o = make_ushort4(f2bf(tile[lc + 0][lr]), f2bf(tile[lc + 1][lr]),
                           f2bf(tile[lc + 2][lr]), f2bf(tile[lc + 3][lr]));
  *(ushort4*)(out + (size_t)(gc + lr) * R + gr + lc) = o;
}

// zero the scattered accumulator ranges in one launch
__global__ __launch_bounds__(256) void k_zero13(float* __restrict__ ws){
  int i = blockIdx.x * 256 + threadIdx.x;
  if (i < 8192) ws[OFF_SALL + i] = 0.f;                   // s_all + s_norm
  else if (i < 12288) ws[OFF_PLOW + i - 8192] = 0.f;      // P_low..P_all
  else if (i < 13312) ws[OFF_WNORM + i - 12288] = 0.f;
  else if (i < 13328) ws[OFF_ACC + i - 13312] = 0.f;
}

// ---------------- m97-style MFMA core (accumulating): acc += A.B^T tile ----------------
// 128x128 tile, BK=32, linear LDS [128][32] bf16, global_load_lds width-16 staging.
__device__ inline void mfma_core97(const unsigned short* __restrict__ A,
                                   const unsigned short* __restrict__ B,
                                   int row0, int col0,
                                   unsigned short* As, unsigned short* Bs,
                                   f32x4 acc[4][4]){
  int t = threadIdx.x;
  int l = t & 63, w = t >> 6;
  int wrow = w >> 1, wcol = w & 1;
  int g = l >> 4, c15 = l & 15;
  // staging: thread t covers 16B chunk t (rows 0..63) and chunk 256+t (rows 64..127)
  const unsigned short* a0 = A + (size_t)(row0 + (t >> 2)) * 1024 + ((t & 3) << 3);
  const unsigned short* a1 = a0 + (size_t)64 * 1024;
  const unsigned short* b0 = B + (size_t)(col0 + (t >> 2)) * 1024 + ((t & 3) << 3);
  const unsigned short* b1 = b0 + (size_t)64 * 1024;
  unsigned short* asd  = As + (size_t)w * 512;   // wave-uniform LDS bases
  unsigned short* asd1 = asd + 2048;
  unsigned short* bsd  = Bs + (size_t)w * 512;
  unsigned short* bsd1 = bsd + 2048;
  int abase = (wrow * 64 + c15) * 32 + g * 8;
  int bbase = (wcol * 64 + c15) * 32 + g * 8;
  for (int kb = 0; kb < 1024; kb += 32){
    gload16(a0 + kb, asd);
    gload16(a1 + kb, asd1);
    gload16(b0 + kb, bsd);
    gload16(b1 + kb, bsd1);
    __syncthreads();                      // vmcnt(0) drain + barrier: LDS ready
    bf16x8 af[4], bfr[4];
#pragma unroll
    for (int m = 0; m < 4; ++m) af[m]  = *(const bf16x8*)&As[abase + m * 512];
#pragma unroll
    for (int n = 0; n < 4; ++n) bfr[n] = *(const bf16x8*)&Bs[bbase + n * 512];
#pragma unroll
    for (int m = 0; m < 4; ++m)
#pragma unroll
      for (int n = 0; n < 4; ++n)
        acc[m][n] = __builtin_amdgcn_mfma_f32_16x16x32_bf16(af[m], bfr[n], acc[m][n], 0, 0, 0);
    __syncthreads();                      // reads done before next stage overwrites
  }
}

// scores: S[row] += sum_col tanh(z@Wa1 + ba1)[col] * Wa2[col]  (ba2 dropped: softmax-invariant)
// A covers [z_all ; z_normal] (M = 8192)
__global__ __launch_bounds__(256) void k_scores_bf(const unsigned short* __restrict__ Zbf,
        const unsigned short* __restrict__ Wa1T, const float* __restrict__ ba1,
        const float* __restrict__ Wa2, float* __restrict__ S){
  __shared__ __align__(16) unsigned short smem[8192];
  f32x4 acc[4][4];
  f32x4 zz = {0.f, 0.f, 0.f, 0.f};
#pragma unroll
  for (int m = 0; m < 4; ++m)
#pragma unroll
    for (int n = 0; n < 4; ++n) acc[m][n] = zz;
  int row0 = blockIdx.y * 128, col0 = blockIdx.x * 128;
  mfma_core97(Zbf, Wa1T, row0, col0, smem, smem + 4096, acc);
  int t = threadIdx.x, l = t & 63, w = t >> 6, wrow = w >> 1, wcol = w & 1;
  int g = l >> 4, c15 = l & 15;
#pragma unroll
  for (int m = 0; m < 4; ++m){
#pragma unroll
    for (int r = 0; r < 4; ++r){
      float v = 0.f;
#pragma unroll
      for (int n = 0; n < 4; ++n){
        int col = col0 + wcol * 64 + n * 16 + c15;
        float x = acc[m][n][r] + ba1[col];
        float e = __expf(2.f * x);
        v += (1.f - 2.f / (e + 1.f)) * Wa2[col];
      }
      v += __shfl_xor(v, 1); v += __shfl_xor(v, 2); v += __shfl_xor(v, 4); v += __shfl_xor(v, 8);
      if (c15 == 0) atomicAdd(&S[row0 + wrow * 64 + m * 16 + 4 * g + r], v);
    }
  }
}

// general GEMM: Out = A.B^T (+ A2.B2^T) (+Add) (+bias); optional bf16 mirror. N = 1024.
__global__ __launch_bounds__(256) void k_gemm_bf(const unsigned short* __restrict__ A,
        const unsigned short* __restrict__ B, const unsigned short* __restrict__ A2,
        const unsigned short* __restrict__ B2, const float* __restrict__ Add,
        const float* __restrict__ bias, float* __restrict__ Out,
        unsigned short* __restrict__ OutBf){
  __shared__ __align__(16) unsigned short smem[8192];
  f32x4 acc[4][4];
  f32x4 zz = {0.f, 0.f, 0.f, 0.f};
#pragma unroll
  for (int m = 0; m < 4; ++m)
#pragma unroll
    for (int n = 0; n < 4; ++n) acc[m][n] = zz;
  int row0 = blockIdx.y * 128, col0 = blockIdx.x * 128;
  mfma_core97(A, B, row0, col0, smem, smem + 4096, acc);
  if (A2) mfma_core97(A2, B2, row0, col0, smem, smem + 4096, acc);
  int t = threadIdx.x, l = t & 63, w = t >> 6, wrow = w >> 1, wcol = w & 1;
  int g = l >> 4, c15 = l & 15;
#pragma unroll
  for (int m = 0; m < 4; ++m){
    int row = row0 + wrow * 64 + m * 16 + 4 * g;
#pragma unroll
    for (int n = 0; n < 4; ++n){
      int col = col0 + wcol * 64 + n * 16 + c15;
#pragma unroll
      for (int r = 0; r < 4; ++r){
        float v = acc[m][n][r];
        size_t idx = (size_t)(row + r) * 1024 + col;
        if (Add)  v += Add[idx];
        if (bias) v += bias[col];
        Out[idx] = v;
        if (OutBf) OutBf[idx] = f2bf(v);
      }
    }
  }
}

// NT GEMM M = z_all . C^T with fused per-64col-chunk row (max,sumexp) partials + diag
__global__ __launch_bounds__(256) void k_gemm_lse(const unsigned short* __restrict__ A,
        const unsigned short* __restrict__ B, float2* __restrict__ partials,
        float* __restrict__ diagM){
  __shared__ __align__(16) unsigned short smem[8192];
  f32x4 acc[4][4];
  f32x4 zz = {0.f, 0.f, 0.f, 0.f};
#pragma unroll
  for (int m = 0; m < 4; ++m)
#pragma unroll
    for (int n = 0; n < 4; ++n) acc[m][n] = zz;
  int row0 = blockIdx.y * 128, col0 = blockIdx.x * 128;
  mfma_core97(A, B, row0, col0, smem, smem + 4096, acc);
  int t = threadIdx.x, l = t & 63, w = t >> 6, wrow = w >> 1, wcol = w & 1;
  int g = l >> 4, c15 = l & 15;
  int chunk = blockIdx.x * 2 + wcol;
#pragma unroll
  for (int m = 0; m < 4; ++m){
#pragma unroll
    for (int r = 0; r < 4; ++r){
      float lm = acc[m][0][r];
#pragma unroll
      for (int n = 1; n < 4; ++n) lm = fmaxf(lm, acc[m][n][r]);
      lm = fmaxf(lm, __shfl_xor(lm, 1));
      lm = fmaxf(lm, __shfl_xor(lm, 2));
      lm = fmaxf(lm, __shfl_xor(lm, 4));
      lm = fmaxf(lm, __shfl_xor(lm, 8));
      float ls = 0.f;
#pragma unroll
      for (int n = 0; n < 4; ++n) ls += __expf(acc[m][n][r] - lm);
      ls += __shfl_xor(ls, 1); ls += __shfl_xor(ls, 2); ls += __shfl_xor(ls, 4); ls += __shfl_xor(ls, 8);
      if (c15 == 0)
        partials[(size_t)chunk * BTOT + (row0 + wrow * 64 + m * 16 + 4 * g + r)] = make_float2(lm, ls);
    }
  }
  if (blockIdx.x == blockIdx.y && wrow == wcol && ((c15 >> 2) == g)){
#pragma unroll
    for (int m = 0; m < 4; ++m)
      diagM[row0 + wrow * 64 + m * 16 + c15] = acc[m][m][c15 & 3];
  }
}

// ---------------- softmax stats (register-resident, one global pass) ----------------
// stats: 0 ml, 1 tl, 2 mh, 3 th, 4 ma, 5 ta, 6 mn, 7 tn, 8 sl=exp(ml-ma), 9 sh=exp(mh-ma)
__global__ __launch_bounds__(256) void k_stats(const float* __restrict__ s_all,
        const float* __restrict__ s_norm, float* __restrict__ e_grp,
        float* __restrict__ e_norm, float* __restrict__ stats){
  __shared__ float sb[4];
  int t = threadIdx.x;
  float va[16], vn[16];
#pragma unroll
  for (int j = 0; j < 16; ++j) va[j] = s_all[t + 256 * j];
#pragma unroll
  for (int j = 0; j < 16; ++j) vn[j] = s_norm[t + 256 * j];
  float m = -1e30f;
#pragma unroll
  for (int j = 0; j < 8; ++j) m = fmaxf(m, va[j]);
  float ml = block_maxf(m, sb);
  m = -1e30f;
#pragma unroll
  for (int j = 8; j < 16; ++j) m = fmaxf(m, va[j]);
  float mh = block_maxf(m, sb);
  m = -1e30f;
#pragma unroll
  for (int j = 0; j < 16; ++j) m = fmaxf(m, vn[j]);
  float mn = block_maxf(m, sb);
  float ma = fmaxf(ml, mh);
  float a = 0.f;
#pragma unroll
  for (int j = 0; j < 8; ++j){ float e = __expf(va[j] - ml); e_grp[t + 256 * j] = e; a += e; }
  float tl = block_sum(a, sb);
  a = 0.f;
#pragma unroll
  for (int j = 8; j < 16; ++j){ float e = __expf(va[j] - mh); e_grp[t + 256 * j] = e; a += e; }
  float th = block_sum(a, sb);
  a = 0.f;
#pragma unroll
  for (int j = 0; j < 16; ++j){ float e = __expf(vn[j] - mn); e_norm[t + 256 * j] = e; a += e; }
  float tn = block_sum(a, sb);
  if (t == 0){
    float sl = __expf(ml - ma), sh = __expf(mh - ma);
    stats[0] = ml; stats[1] = tl; stats[2] = mh; stats[3] = th;
    stats[4] = ma; stats[5] = tl * sl + th * sh; stats[6] = mn; stats[7] = tn;
    stats[8] = sl; stats[9] = sh;
  }
}

// P_g[col] = sum_rows e_row * x[row][col]; groups: 0 low, 1 high, 2 norm.
__global__ __launch_bounds__(256) void k_pvec(const float* __restrict__ z_all,
        const float* __restrict__ z_normal, const float* __restrict__ e_grp,
        const float* __restrict__ e_norm, float* __restrict__ P){
  int gz = blockIdx.z;
  const float* X; const float* E; float* Pg; int nr;
  if (gz == 0){ X = z_all;                         E = e_grp;        Pg = P;        nr = BLOW; }
  else if (gz == 1){ X = z_all + (size_t)BLOW * D; E = e_grp + BLOW; Pg = P + 1024; nr = BLOW; }
  else { X = z_normal;                             E = e_norm;       Pg = P + 2048; nr = BTOT; }
  int r0 = blockIdx.y * 16;
  if (r0 >= nr) return;
  int c4 = threadIdx.x * 4;
  float4 a = make_float4(0.f, 0.f, 0.f, 0.f);
#pragma unroll 4
  for (int r = r0; r < r0 + 16; ++r){
    float e = E[r];
    float4 x = *(const float4*)(X + (size_t)r * D + c4);
    a.x = fmaf(e, x.x, a.x); a.y = fmaf(e, x.y, a.y);
    a.z = fmaf(e, x.z, a.z); a.w = fmaf(e, x.w, a.w);
  }
  atomicAdd(&Pg[c4 + 0], a.x);
  atomicAdd(&Pg[c4 + 1], a.y);
  atomicAdd(&Pg[c4 + 2], a.z);
  atomicAdd(&Pg[c4 + 3], a.w);
}

// P_all = sl*P_low + sh*P_high; znv = P_norm / tn; biasC = 2 b0 + b1
__global__ __launch_bounds__(256) void k_smallvec(const float* __restrict__ P,
        const float* __restrict__ stats, const float* __restrict__ b0,
        const float* __restrict__ b1, float* __restrict__ P_all,
        float* __restrict__ znv, float* __restrict__ biasC){
  int c = blockIdx.x * 256 + threadIdx.x;
  znv[c] = P[2048 + c] / stats[7];
  biasC[c] = 2.f * b0[c] + b1[c];
  P_all[c] = stats[8] * P[c] + stats[9] * P[1024 + c];
}

__global__ __launch_bounds__(256) void k_wnorm(const float* __restrict__ znv,
        const float* __restrict__ W0, float* __restrict__ w_norm){
  int col = blockIdx.x * 256 + threadIdx.x;
  int kc = blockIdx.y;
  float a = 0.f;
  for (int k = kc * 128; k < kc * 128 + 128; ++k)
    a = fmaf(znv[k], W0[(size_t)k * D + col], a);
  atomicAdd(&w_norm[col], a);
}

// z_hat / z_tumor rows (bf16 out) + cos(z,z_hat), cos(z,z_bar) reductions
__global__ __launch_bounds__(256) void k_zhat(const float* __restrict__ z_all,
        const float* __restrict__ z_bar, const float* __restrict__ e_grp,
        const float* __restrict__ stats,
        const float* __restrict__ P_low, const float* __restrict__ P_high,
        const float* __restrict__ P_all, unsigned short* __restrict__ zhat_bf,
        unsigned short* __restrict__ ztum_bf, float* __restrict__ nz_arr,
        float* __restrict__ accum){
  __shared__ float sb[4];
  int i = blockIdx.x, t = threadIdx.x;
  const float* Pg = (i < BLOW) ? P_low : P_high;
  float Tg = (i < BLOW) ? stats[1] : stats[3];
  float Ta = stats[5];
  float eg = e_grp[i];
  float ea = eg * ((i < BLOW) ? stats[8] : stats[9]);
  float ig = 1.f / (Tg - eg), ia = 1.f / (Ta - ea);
  size_t base = (size_t)i * D;
  float4 x  = ((const float4*)(z_all + base))[t];
  float4 pg = ((const float4*)Pg)[t];
  float4 pa = ((const float4*)P_all)[t];
  float4 zb = ((const float4*)(z_bar + base))[t];
  float4 zh, zt;
  zh.x = (pg.x - eg * x.x) * ig; zh.y = (pg.y - eg * x.y) * ig;
  zh.z = (pg.z - eg * x.z) * ig; zh.w = (pg.w - eg * x.w) * ig;
  zt.x = (pa.x - ea * x.x) * ia; zt.y = (pa.y - ea * x.y) * ia;
  zt.z = (pa.z - ea * x.z) * ia; zt.w = (pa.w - ea * x.w) * ia;
  *(ushort4*)(zhat_bf + base + t * 4) = make_ushort4(f2bf(zh.x), f2bf(zh.y), f2bf(zh.z), f2bf(zh.w));
  *(ushort4*)(ztum_bf + base + t * 4) = make_ushort4(f2bf(zt.x), f2bf(zt.y), f2bf(zt.z), f2bf(zt.w));
  float nz2 = x.x*x.x + x.y*x.y + x.z*x.z + x.w*x.w;
  float nh2 = zh.x*zh.x + zh.y*zh.y + zh.z*zh.z + zh.w*zh.w;
  float dzh = x.x*zh.x + x.y*zh.y + x.z*zh.z + x.w*zh.w;
  float nb2 = zb.x*zb.x + zb.y*zb.y + zb.z*zb.z + zb.w*zb.w;
  float dzb = x.x*zb.x + x.y*zb.y + x.z*zb.z + x.w*zb.w;
  float s_nz2 = block_sum(nz2, sb);
  float s_nh2 = block_sum(nh2, sb);
  float s_dzh = block_sum(dzh, sb);
  float s_nb2 = block_sum(nb2, sb);
  float s_dzb = block_sum(dzb, sb);
  if (t == 0){
    float nz = sqrtf(s_nz2);
    nz_arr[i] = nz;
    float denA = fmaxf(nz, 1e-8f) * fmaxf(sqrtf(s_nh2), 1e-8f);
    float denB = fmaxf(nz, 1e-8f) * fmaxf(sqrtf(s_nb2), 1e-8f);
    atomicAdd(&accum[0], (1.f - s_dzh / denA) + (1.f - s_dzb / denB));
  }
}

// per-row: dt = z.pt, ||pt||, dpn = z.(C+w), ||C+w||, g = z.w; hinge accumulation
__global__ __launch_bounds__(256) void k_rowred2(const float* __restrict__ z_all,
        const float* __restrict__ PT, const float* __restrict__ C,
        const float* __restrict__ w_norm, const float* __restrict__ nz_arr,
        float* __restrict__ dt_arr, float* __restrict__ g_arr, float* __restrict__ accum){
  __shared__ float sb[4];
  int i = blockIdx.x, t = threadIdx.x;
  size_t base = (size_t)i * D;
  float4 x  = ((const float4*)(z_all + base))[t];
  float4 pt = ((const float4*)(PT + base))[t];
  float4 c  = ((const float4*)(C + base))[t];
  float4 wv = ((const float4*)w_norm)[t];
  float4 pn = make_float4(c.x + wv.x, c.y + wv.y, c.z + wv.z, c.w + wv.w);
  float dt   = x.x*pt.x + x.y*pt.y + x.z*pt.z + x.w*pt.w;
  float npt2 = pt.x*pt.x + pt.y*pt.y + pt.z*pt.z + pt.w*pt.w;
  float dpn  = x.x*pn.x + x.y*pn.y + x.z*pn.z + x.w*pn.w;
  float npn2 = pn.x*pn.x + pn.y*pn.y + pn.z*pn.z + pn.w*pn.w;
  float gg   = x.x*wv.x + x.y*wv.y + x.z*wv.z + x.w*wv.w;
  float s_dt   = block_sum(dt, sb);
  float s_npt2 = block_sum(npt2, sb);
  float s_dpn  = block_sum(dpn, sb);
  float s_npn2 = block_sum(npn2, sb);
  float s_g    = block_sum(gg, sb);
  if (t == 0){
    dt_arr[i] = s_dt; g_arr[i] = s_g;
    float nz = fmaxf(nz_arr[i], 1e-8f);
    float ct = s_dt  / (nz * fmaxf(sqrtf(s_npt2), 1e-8f));
    float cn = s_dpn / (nz * fmaxf(sqrtf(s_npn2), 1e-8f));
    atomicAdd(&accum[1], fmaxf(0.f, 1.f - (ct - cn)));
  }
}

__global__ __launch_bounds__(256) void k_combine(const float2* __restrict__ partials,
        const float* __restrict__ diagM, const float* __restrict__ dt,
        const float* __restrict__ g, float* __restrict__ accum){
  __shared__ float sb[4];
  int i = blockIdx.x * 256 + threadIdx.x;
  float m = -1e30f, S = 0.f;
  for (int c = 0; c < NCHUNK; ++c){
    float2 p = partials[(size_t)c * BTOT + i];
    float nm = fmaxf(m, p.x);
    S = S * __expf(m - nm) + p.y * __expf(p.x - nm);
    m = nm;
  }
  float vold = diagM[i];
  float vnew = dt[i] - g[i];
  float nm = fmaxf(m, vnew);
  float S2 = S * __expf(m - nm) - __expf(vold - nm) + __expf(vnew - nm);
  float lse = g[i] + nm + logf(S2);
  float contrib = lse - dt[i];
  float tot = block_sum(contrib, sb);
  if (threadIdx.x == 0) atomicAdd(&accum[2], tot);
}

__global__ void k_final(const float* __restrict__ accum, float* __restrict__ out){
  out[0] = accum[2] / (float)BTOT;
  out[1] = (accum[0] + accum[1]) / (float)BTOT;
}

// ---------------- launch ----------------
extern "C" void kernel_launch(void* const* d_in, const int* in_sizes, int n_in,
                              void* d_out, int out_size, void* d_ws, size_t ws_size,
                              hipStream_t stream){
  const float* z_low    = (const float*)d_in[0];
  const float* z_high   = (const float*)d_in[1];
  const float* z_bar    = (const float*)d_in[2];
  const float* z_normal = (const float*)d_in[3];
  const float* Wa1      = (const float*)d_in[4];
  const float* ba1      = (const float*)d_in[5];
  const float* Wa2      = (const float*)d_in[6];
  const float* ba2      = (const float*)d_in[7];   // dropped: softmax shift-invariant
  const float* W0       = (const float*)d_in[8];
  const float* b0       = (const float*)d_in[9];
  const float* W1       = (const float*)d_in[10];
  const float* b1       = (const float*)d_in[11];
  float* ws = (float*)d_ws;
  unsigned short* bw = (unsigned short*)(ws + BF_BASE_F);
  float* out = (float*)d_out;
  (void)ba2;

  k_prep<<<dim3(BTOT, 1, 3), dim3(256), 0, stream>>>(z_low, z_high, z_normal, z_bar,
      ws + OFF_ZALL, bw + BF_ZALLN, bw + BF_ZBAR);
  k_tconv3<<<dim3(32, 32, 3), dim3(256), 0, stream>>>(W0, W1, Wa1,
      bw + BF_W0T, bw + BF_W1T, bw + BF_WA1T);
  k_zero13<<<dim3(53), dim3(256), 0, stream>>>(ws);

  // scores over [z_all ; z_normal] in one call (M = 8192)
  k_scores_bf<<<dim3(2, 64), dim3(256), 0, stream>>>(bw + BF_ZALLN, bw + BF_WA1T,
      ba1, Wa2, ws + OFF_SALL);

  k_stats<<<dim3(1), dim3(256), 0, stream>>>(ws + OFF_SALL, ws + OFF_SNORM,
      ws + OFF_EGRP, ws + OFF_ENORM, ws + OFF_STATS);

  k_pvec<<<dim3(1, 256, 3), dim3(256), 0, stream>>>(ws + OFF_ZALL, z_normal,
      ws + OFF_EGRP, ws + OFF_ENORM, ws + OFF_PLOW);

  k_smallvec<<<dim3(4), dim3(256), 0, stream>>>(ws + OFF_PLOW, ws + OFF_STATS,
      b0, b1, ws + OFF_PALL, ws + OFF_ZNV, ws + OFF_BIASC);

  k_wnorm<<<dim3(4, 8), dim3(256), 0, stream>>>(ws + OFF_ZNV, W0, ws + OFF_WNORM);

  k_zhat<<<dim3(BTOT), dim3(256), 0, stream>>>(ws + OFF_ZALL, z_bar,
      ws + OFF_EGRP, ws + OFF_STATS,
      ws + OFF_PLOW, ws + OFF_PHIGH, ws + OFF_PALL,
      bw + BF_ZHAT, bw + BF_ZTUM, ws + OFF_NZ, ws + OFF_ACC);

  // C = z_hat @ W0 + z_bar @ W1 + (2 b0 + b1)   (one kernel, two core passes)
  k_gemm_bf<<<dim3(8, 32), dim3(256), 0, stream>>>(bw + BF_ZHAT, bw + BF_W0T,
      bw + BF_ZBAR, bw + BF_W1T, nullptr, ws + OFF_BIASC, ws + OFF_C, bw + BF_C);
  // PT = z_tumor @ W0 + C
  k_gemm_bf<<<dim3(8, 32), dim3(256), 0, stream>>>(bw + BF_ZTUM, bw + BF_W0T,
      nullptr, nullptr, ws + OFF_C, nullptr, ws + OFF_PT, nullptr);

  k_rowred2<<<dim3(BTOT), dim3(256), 0, stream>>>(ws + OFF_ZALL, ws + OFF_PT,
      ws + OFF_C, ws + OFF_WNORM, ws + OFF_NZ, ws + OFF_DT, ws + OFF_G, ws + OFF_ACC);

  k_gemm_lse<<<dim3(32, 32), dim3(256), 0, stream>>>(bw + BF_ZALLN, bw + BF_C,
      (float2*)(ws + OFF_PART), ws + OFF_DIAG);

  k_combine<<<dim3(16), dim3(256), 0, stream>>>((const float2*)(ws + OFF_PART),
      ws + OFF_DIAG, ws + OFF_DT, ws + OFF_G, ws + OFF_ACC);

  k_final<<<dim3(1), dim3(1), 0, stream>>>(ws + OFF_ACC, out);
}

// Round 6
// 409.277 us; speedup vs baseline: 3.1279x; 1.1120x over previous
//
#include <hip/hip_runtime.h>
#include <math.h>

#define D     1024
#define H     256
#define BLOW  2048
#define BTOT  4096
#define NCHUNK 64   // 4096 / 64 col chunks (per-wave) in the NT-LSE GEMM

using bf16x8 = __attribute__((ext_vector_type(8))) __bf16;
using f32x4  = __attribute__((ext_vector_type(4))) float;

// ---------------- workspace layout ----------------
// fp32 region (float units)
static const size_t OFF_ZALL = 0;                 // 4096*1024
static const size_t OFF_C    = 4194304;           // C fp32
static const size_t OFF_PT   = 8388608;           // pred_tumor fp32
static const size_t T0       = 12582912;
static const size_t OFF_SALL = T0;                // 4096  (s_norm follows contiguously)
static const size_t OFF_SNORM= T0 + 4096;         // 4096
static const size_t OFF_EGRP = T0 + 8192;         // 4096
static const size_t OFF_ENORM= T0 + 16384;        // 4096
static const size_t OFF_PLOW = T0 + 20480;        // 1024 x4 contiguous
static const size_t OFF_PHIGH= T0 + 21504;
static const size_t OFF_PNORM= T0 + 22528;
static const size_t OFF_PALL = T0 + 23552;
static const size_t OFF_ZNV  = T0 + 24576;        // 1024
static const size_t OFF_WNORM= T0 + 25600;        // 1024
static const size_t OFF_BIASC= T0 + 26624;        // 1024
static const size_t OFF_STATS= T0 + 27648;        // 16
static const size_t OFF_ACC  = T0 + 27664;        // 16
static const size_t OFF_NZ   = T0 + 27680;        // 4096
static const size_t OFF_DT   = T0 + 31776;        // 4096
static const size_t OFF_G    = T0 + 35872;        // 4096
static const size_t OFF_DIAG = T0 + 39968;        // 4096
static const size_t OFF_PART = T0 + 44064;        // float2[64][4096] = 524288 floats
static const size_t BF_BASE_F = 13160448;         // bf16 region starts here (float units)
// bf16 offsets (ushort units)
static const size_t BF_ZALLN= 0;                  // [z_all(4096) ; z_normal(4096)] x 1024
static const size_t BF_ZHAT = 8388608;
static const size_t BF_ZTUM = 12582912;
static const size_t BF_ZBAR = 16777216;
static const size_t BF_C    = 20971520;
static const size_t BF_W0T  = 25165824;           // 1024x1024
static const size_t BF_W1T  = 26214400;
static const size_t BF_WA1T = 27262976;           // 256x1024

// ---------------- helpers ----------------
__device__ inline unsigned short f2bf(float f){
  unsigned u = __float_as_uint(f);
  u += 0x7fffu + ((u >> 16) & 1u);
  return (unsigned short)(u >> 16);
}
__device__ inline float wave_sum(float v){
#pragma unroll
  for (int o = 32; o > 0; o >>= 1) v += __shfl_xor(v, o);
  return v;
}
__device__ inline float wave_maxf(float v){
#pragma unroll
  for (int o = 32; o > 0; o >>= 1) v = fmaxf(v, __shfl_xor(v, o));
  return v;
}
__device__ inline float block_sum(float v, float* sb){
  v = wave_sum(v);
  __syncthreads();
  if ((threadIdx.x & 63) == 0) sb[threadIdx.x >> 6] = v;
  __syncthreads();
  return sb[0] + sb[1] + sb[2] + sb[3];
}
__device__ inline float block_maxf(float v, float* sb){
  v = wave_maxf(v);
  __syncthreads();
  if ((threadIdx.x & 63) == 0) sb[threadIdx.x >> 6] = v;
  __syncthreads();
  return fmaxf(fmaxf(sb[0], sb[1]), fmaxf(sb[2], sb[3]));
}

// async global->LDS, 16 B per lane (dest = wave-uniform base + lane*16)
__device__ inline void gload16(const unsigned short* g, unsigned short* l){
  __builtin_amdgcn_global_load_lds(
      (const __attribute__((address_space(1))) unsigned int*)g,
      (__attribute__((address_space(3))) unsigned int*)l, 16, 0, 0);
}

// ---------------- fused prep: concat+conv / conv z_normal / conv z_bar ----------------
__global__ __launch_bounds__(256) void k_prep(const float* __restrict__ zl,
        const float* __restrict__ zh, const float* __restrict__ znorm,
        const float* __restrict__ zbar, float* __restrict__ za,
        unsigned short* __restrict__ zalln_bf, unsigned short* __restrict__ zbar_bf){
  int row = blockIdx.x, t = threadIdx.x, job = blockIdx.z;
  if (job == 0){
    const float4* src = (const float4*)((row < BLOW) ? (zl + (size_t)row * D)
                                                     : (zh + (size_t)(row - BLOW) * D));
    float4 v = src[t];
    ((float4*)(za + (size_t)row * D))[t] = v;
    *(ushort4*)(zalln_bf + (size_t)row * D + t * 4) =
        make_ushort4(f2bf(v.x), f2bf(v.y), f2bf(v.z), f2bf(v.w));
  } else if (job == 1){
    float4 v = ((const float4*)(znorm + (size_t)row * D))[t];
    *(ushort4*)(zalln_bf + (size_t)(BTOT + row) * D + t * 4) =
        make_ushort4(f2bf(v.x), f2bf(v.y), f2bf(v.z), f2bf(v.w));
  } else {
    float4 v = ((const float4*)(zbar + (size_t)row * D))[t];
    *(ushort4*)(zbar_bf + (size_t)row * D + t * 4) =
        make_ushort4(f2bf(v.x), f2bf(v.y), f2bf(v.z), f2bf(v.w));
  }
}

// transpose+convert all three weights in one launch
__global__ __launch_bounds__(256) void k_tconv3(const float* __restrict__ W0,
        const float* __restrict__ W1, const float* __restrict__ Wa1,
        unsigned short* __restrict__ W0T, unsigned short* __restrict__ W1T,
        unsigned short* __restrict__ Wa1T){
  __shared__ float tile[32][33];
  int z = blockIdx.z;
  const float* in; unsigned short* out; int R, C;
  if (z == 0){ in = W0; out = W0T; R = D; C = D; }
  else if (z == 1){ in = W1; out = W1T; R = D; C = D; }
  else { if (blockIdx.x >= 8) return; in = Wa1; out = Wa1T; R = D; C = H; }
  int t = threadIdx.x;
  int lr = t >> 3;
  int lc = (t & 7) << 2;
  int gr = blockIdx.y * 32, gc = blockIdx.x * 32;
  float4 v = *(const float4*)(in + (size_t)(gr + lr) * C + gc + lc);
  tile[lr][lc + 0] = v.x; tile[lr][lc + 1] = v.y; tile[lr][lc + 2] = v.z; tile[lr][lc + 3] = v.w;
  __syncthreads();
  ushort4 o = make_ushort4(f2bf(tile[lc + 0][lr]), f2bf(tile[lc + 1][lr]),
                           f2bf(tile[lc + 2][lr]), f2bf(tile[lc + 3][lr]));
  *(ushort4*)(out + (size_t)(gc + lr) * R + gr + lc) = o;
}

// zero the scattered accumulator ranges in one launch
__global__ __launch_bounds__(256) void k_zero13(float* __restrict__ ws){
  int i = blockIdx.x * 256 + threadIdx.x;
  if (i < 8192) ws[OFF_SALL + i] = 0.f;                   // s_all + s_norm
  else if (i < 12288) ws[OFF_PLOW + i - 8192] = 0.f;      // P_low..P_all
  else if (i < 13312) ws[OFF_WNORM + i - 12288] = 0.f;
  else if (i < 13328) ws[OFF_ACC + i - 13312] = 0.f;
}

// ---------------- double-buffered 2-phase MFMA core: acc += A.B^T tile ----------------
// 128x128 tile, BK=32, linear LDS [128][32] bf16 per operand, 2 buffers.
// Per K-step: issue next-tile global_load_lds into the OTHER buffer, then
// ds_read+MFMA the current one, then ONE barrier (drains prefetch after the
// MFMA phase covered its latency).
// lds layout: buf0 { A[4096] B[4096] } buf1 { A[4096] B[4096] }  (ushorts)
__device__ inline void mfma_core_db(const unsigned short* __restrict__ A,
                                    const unsigned short* __restrict__ B,
                                    int row0, int col0,
                                    unsigned short* lds,
                                    f32x4 acc[4][4]){
  int t = threadIdx.x;
  int l = t & 63, w = t >> 6;
  int wrow = w >> 1, wcol = w & 1;
  int g = l >> 4, c15 = l & 15;
  // staging: thread t covers 16B chunk of row (t>>2), cols (t&3)*8..+8; +64 rows second half
  const unsigned short* a0 = A + (size_t)(row0 + (t >> 2)) * 1024 + ((t & 3) << 3);
  const unsigned short* a1 = a0 + (size_t)64 * 1024;
  const unsigned short* b0 = B + (size_t)(col0 + (t >> 2)) * 1024 + ((t & 3) << 3);
  const unsigned short* b1 = b0 + (size_t)64 * 1024;
  int sd = w * 512;                      // wave-uniform staging base (1 KB per wave)
  int abase = (wrow * 64 + c15) * 32 + g * 8;
  int bbase = 4096 + (wcol * 64 + c15) * 32 + g * 8;
  unsigned short* buf = lds;
  unsigned short* nxt = lds + 8192;
  // prologue: stage tile 0 into buf
  gload16(a0, buf + sd);
  gload16(a1, buf + 2048 + sd);
  gload16(b0, buf + 4096 + sd);
  gload16(b1, buf + 6144 + sd);
  __syncthreads();
  for (int kb = 0; kb < 1024; kb += 32){
    if (kb + 32 < 1024){
      gload16(a0 + kb + 32, nxt + sd);
      gload16(a1 + kb + 32, nxt + 2048 + sd);
      gload16(b0 + kb + 32, nxt + 4096 + sd);
      gload16(b1 + kb + 32, nxt + 6144 + sd);
    }
    bf16x8 af[4], bfr[4];
#pragma unroll
    for (int m = 0; m < 4; ++m) af[m]  = *(const bf16x8*)&buf[abase + m * 512];
#pragma unroll
    for (int n = 0; n < 4; ++n) bfr[n] = *(const bf16x8*)&buf[bbase + n * 512];
#pragma unroll
    for (int m = 0; m < 4; ++m)
#pragma unroll
      for (int n = 0; n < 4; ++n)
        acc[m][n] = __builtin_amdgcn_mfma_f32_16x16x32_bf16(af[m], bfr[n], acc[m][n], 0, 0, 0);
    __syncthreads();   // our ds_reads of buf done; all waves' gloads into nxt done
    unsigned short* tmp = buf; buf = nxt; nxt = tmp;
  }
}

// scores: S[row] += sum_col tanh(z@Wa1 + ba1)[col] * Wa2[col]  (ba2 dropped: softmax-invariant)
__global__ __launch_bounds__(256) void k_scores_bf(const unsigned short* __restrict__ Zbf,
        const unsigned short* __restrict__ Wa1T, const float* __restrict__ ba1,
        const float* __restrict__ Wa2, float* __restrict__ S){
  __shared__ __align__(16) unsigned short smem[16384];
  f32x4 acc[4][4];
  f32x4 zz = {0.f, 0.f, 0.f, 0.f};
#pragma unroll
  for (int m = 0; m < 4; ++m)
#pragma unroll
    for (int n = 0; n < 4; ++n) acc[m][n] = zz;
  int row0 = blockIdx.y * 128, col0 = blockIdx.x * 128;
  mfma_core_db(Zbf, Wa1T, row0, col0, smem, acc);
  int t = threadIdx.x, l = t & 63, w = t >> 6, wrow = w >> 1, wcol = w & 1;
  int g = l >> 4, c15 = l & 15;
#pragma unroll
  for (int m = 0; m < 4; ++m){
#pragma unroll
    for (int r = 0; r < 4; ++r){
      float v = 0.f;
#pragma unroll
      for (int n = 0; n < 4; ++n){
        int col = col0 + wcol * 64 + n * 16 + c15;
        float x = acc[m][n][r] + ba1[col];
        float e = __expf(2.f * x);
        v += (1.f - 2.f / (e + 1.f)) * Wa2[col];
      }
      v += __shfl_xor(v, 1); v += __shfl_xor(v, 2); v += __shfl_xor(v, 4); v += __shfl_xor(v, 8);
      if (c15 == 0) atomicAdd(&S[row0 + wrow * 64 + m * 16 + 4 * g + r], v);
    }
  }
}

// merged C + PT kernel (3 core passes, N = 1024):
// pass1 zhat@W0, pass2 zbar@W1 -> C = acc + biasC (fp32 + bf16 mirror)
// pass3 ztum@W0 -> PT = acc + biasC
__global__ __launch_bounds__(256) void k_gemm_cpt(const unsigned short* __restrict__ Zhat,
        const unsigned short* __restrict__ Zbar, const unsigned short* __restrict__ Ztum,
        const unsigned short* __restrict__ W0T, const unsigned short* __restrict__ W1T,
        const float* __restrict__ biasC, float* __restrict__ C,
        unsigned short* __restrict__ Cbf, float* __restrict__ PT){
  __shared__ __align__(16) unsigned short smem[16384];
  f32x4 acc[4][4];
  f32x4 zz = {0.f, 0.f, 0.f, 0.f};
#pragma unroll
  for (int m = 0; m < 4; ++m)
#pragma unroll
    for (int n = 0; n < 4; ++n) acc[m][n] = zz;
  int row0 = blockIdx.y * 128, col0 = blockIdx.x * 128;
  mfma_core_db(Zhat, W0T, row0, col0, smem, acc);
  mfma_core_db(Zbar, W1T, row0, col0, smem, acc);
  int t = threadIdx.x, l = t & 63, w = t >> 6, wrow = w >> 1, wcol = w & 1;
  int g = l >> 4, c15 = l & 15;
#pragma unroll
  for (int m = 0; m < 4; ++m){
    int row = row0 + wrow * 64 + m * 16 + 4 * g;
#pragma unroll
    for (int n = 0; n < 4; ++n){
      int col = col0 + wcol * 64 + n * 16 + c15;
      float bv = biasC[col];
#pragma unroll
      for (int r = 0; r < 4; ++r){
        float v = acc[m][n][r] + bv;
        size_t idx = (size_t)(row + r) * 1024 + col;
        C[idx] = v;
        Cbf[idx] = f2bf(v);
      }
    }
  }
  mfma_core_db(Ztum, W0T, row0, col0, smem, acc);
#pragma unroll
  for (int m = 0; m < 4; ++m){
    int row = row0 + wrow * 64 + m * 16 + 4 * g;
#pragma unroll
    for (int n = 0; n < 4; ++n){
      int col = col0 + wcol * 64 + n * 16 + c15;
      float bv = biasC[col];
#pragma unroll
      for (int r = 0; r < 4; ++r){
        size_t idx = (size_t)(row + r) * 1024 + col;
        PT[idx] = acc[m][n][r] + bv;
      }
    }
  }
}

// NT GEMM M = z_all . C^T with fused per-64col-chunk row (max,sumexp) partials + diag
__global__ __launch_bounds__(256) void k_gemm_lse(const unsigned short* __restrict__ A,
        const unsigned short* __restrict__ B, float2* __restrict__ partials,
        float* __restrict__ diagM){
  __shared__ __align__(16) unsigned short smem[16384];
  f32x4 acc[4][4];
  f32x4 zz = {0.f, 0.f, 0.f, 0.f};
#pragma unroll
  for (int m = 0; m < 4; ++m)
#pragma unroll
    for (int n = 0; n < 4; ++n) acc[m][n] = zz;
  int row0 = blockIdx.y * 128, col0 = blockIdx.x * 128;
  mfma_core_db(A, B, row0, col0, smem, acc);
  int t = threadIdx.x, l = t & 63, w = t >> 6, wrow = w >> 1, wcol = w & 1;
  int g = l >> 4, c15 = l & 15;
  int chunk = blockIdx.x * 2 + wcol;
#pragma unroll
  for (int m = 0; m < 4; ++m){
#pragma unroll
    for (int r = 0; r < 4; ++r){
      float lm = acc[m][0][r];
#pragma unroll
      for (int n = 1; n < 4; ++n) lm = fmaxf(lm, acc[m][n][r]);
      lm = fmaxf(lm, __shfl_xor(lm, 1));
      lm = fmaxf(lm, __shfl_xor(lm, 2));
      lm = fmaxf(lm, __shfl_xor(lm, 4));
      lm = fmaxf(lm, __shfl_xor(lm, 8));
      float ls = 0.f;
#pragma unroll
      for (int n = 0; n < 4; ++n) ls += __expf(acc[m][n][r] - lm);
      ls += __shfl_xor(ls, 1); ls += __shfl_xor(ls, 2); ls += __shfl_xor(ls, 4); ls += __shfl_xor(ls, 8);
      if (c15 == 0)
        partials[(size_t)chunk * BTOT + (row0 + wrow * 64 + m * 16 + 4 * g + r)] = make_float2(lm, ls);
    }
  }
  if (blockIdx.x == blockIdx.y && wrow == wcol && ((c15 >> 2) == g)){
#pragma unroll
    for (int m = 0; m < 4; ++m)
      diagM[row0 + wrow * 64 + m * 16 + c15] = acc[m][m][c15 & 3];
  }
}

// ---------------- softmax stats (register-resident, one global pass) ----------------
// stats: 0 ml, 1 tl, 2 mh, 3 th, 4 ma, 5 ta, 6 mn, 7 tn, 8 sl=exp(ml-ma), 9 sh=exp(mh-ma)
__global__ __launch_bounds__(256) void k_stats(const float* __restrict__ s_all,
        const float* __restrict__ s_norm, float* __restrict__ e_grp,
        float* __restrict__ e_norm, float* __restrict__ stats){
  __shared__ float sb[4];
  int t = threadIdx.x;
  float va[16], vn[16];
#pragma unroll
  for (int j = 0; j < 16; ++j) va[j] = s_all[t + 256 * j];
#pragma unroll
  for (int j = 0; j < 16; ++j) vn[j] = s_norm[t + 256 * j];
  float m = -1e30f;
#pragma unroll
  for (int j = 0; j < 8; ++j) m = fmaxf(m, va[j]);
  float ml = block_maxf(m, sb);
  m = -1e30f;
#pragma unroll
  for (int j = 8; j < 16; ++j) m = fmaxf(m, va[j]);
  float mh = block_maxf(m, sb);
  m = -1e30f;
#pragma unroll
  for (int j = 0; j < 16; ++j) m = fmaxf(m, vn[j]);
  float mn = block_maxf(m, sb);
  float ma = fmaxf(ml, mh);
  float a = 0.f;
#pragma unroll
  for (int j = 0; j < 8; ++j){ float e = __expf(va[j] - ml); e_grp[t + 256 * j] = e; a += e; }
  float tl = block_sum(a, sb);
  a = 0.f;
#pragma unroll
  for (int j = 8; j < 16; ++j){ float e = __expf(va[j] - mh); e_grp[t + 256 * j] = e; a += e; }
  float th = block_sum(a, sb);
  a = 0.f;
#pragma unroll
  for (int j = 0; j < 16; ++j){ float e = __expf(vn[j] - mn); e_norm[t + 256 * j] = e; a += e; }
  float tn = block_sum(a, sb);
  if (t == 0){
    float sl = __expf(ml - ma), sh = __expf(mh - ma);
    stats[0] = ml; stats[1] = tl; stats[2] = mh; stats[3] = th;
    stats[4] = ma; stats[5] = tl * sl + th * sh; stats[6] = mn; stats[7] = tn;
    stats[8] = sl; stats[9] = sh;
  }
}

// P_g[col] = sum_rows e_row * x[row][col]; groups: 0 low, 1 high, 2 norm.
__global__ __launch_bounds__(256) void k_pvec(const float* __restrict__ z_all,
        const float* __restrict__ z_normal, const float* __restrict__ e_grp,
        const float* __restrict__ e_norm, float* __restrict__ P){
  int gz = blockIdx.z;
  const float* X; const float* E; float* Pg; int nr;
  if (gz == 0){ X = z_all;                         E = e_grp;        Pg = P;        nr = BLOW; }
  else if (gz == 1){ X = z_all + (size_t)BLOW * D; E = e_grp + BLOW; Pg = P + 1024; nr = BLOW; }
  else { X = z_normal;                             E = e_norm;       Pg = P + 2048; nr = BTOT; }
  int r0 = blockIdx.y * 16;
  if (r0 >= nr) return;
  int c4 = threadIdx.x * 4;
  float4 a = make_float4(0.f, 0.f, 0.f, 0.f);
#pragma unroll 4
  for (int r = r0; r < r0 + 16; ++r){
    float e = E[r];
    float4 x = *(const float4*)(X + (size_t)r * D + c4);
    a.x = fmaf(e, x.x, a.x); a.y = fmaf(e, x.y, a.y);
    a.z = fmaf(e, x.z, a.z); a.w = fmaf(e, x.w, a.w);
  }
  atomicAdd(&Pg[c4 + 0], a.x);
  atomicAdd(&Pg[c4 + 1], a.y);
  atomicAdd(&Pg[c4 + 2], a.z);
  atomicAdd(&Pg[c4 + 3], a.w);
}

// P_all = sl*P_low + sh*P_high; znv = P_norm / tn; biasC = 2 b0 + b1
__global__ __launch_bounds__(256) void k_smallvec(const float* __restrict__ P,
        const float* __restrict__ stats, const float* __restrict__ b0,
        const float* __restrict__ b1, float* __restrict__ P_all,
        float* __restrict__ znv, float* __restrict__ biasC){
  int c = blockIdx.x * 256 + threadIdx.x;
  znv[c] = P[2048 + c] / stats[7];
  biasC[c] = 2.f * b0[c] + b1[c];
  P_all[c] = stats[8] * P[c] + stats[9] * P[1024 + c];
}

__global__ __launch_bounds__(256) void k_wnorm(const float* __restrict__ znv,
        const float* __restrict__ W0, float* __restrict__ w_norm){
  int col = blockIdx.x * 256 + threadIdx.x;
  int kc = blockIdx.y;
  float a = 0.f;
  for (int k = kc * 128; k < kc * 128 + 128; ++k)
    a = fmaf(znv[k], W0[(size_t)k * D + col], a);
  atomicAdd(&w_norm[col], a);
}

// z_hat / z_tumor rows (bf16 out) + cos(z,z_hat), cos(z,z_bar) reductions
__global__ __launch_bounds__(256) void k_zhat(const float* __restrict__ z_all,
        const float* __restrict__ z_bar, const float* __restrict__ e_grp,
        const float* __restrict__ stats,
        const float* __restrict__ P_low, const float* __restrict__ P_high,
        const float* __restrict__ P_all, unsigned short* __restrict__ zhat_bf,
        unsigned short* __restrict__ ztum_bf, float* __restrict__ nz_arr,
        float* __restrict__ accum){
  __shared__ float sb[4];
  int i = blockIdx.x, t = threadIdx.x;
  const float* Pg = (i < BLOW) ? P_low : P_high;
  float Tg = (i < BLOW) ? stats[1] : stats[3];
  float Ta = stats[5];
  float eg = e_grp[i];
  float ea = eg * ((i < BLOW) ? stats[8] : stats[9]);
  float ig = 1.f / (Tg - eg), ia = 1.f / (Ta - ea);
  size_t base = (size_t)i * D;
  float4 x  = ((const float4*)(z_all + base))[t];
  float4 pg = ((const float4*)Pg)[t];
  float4 pa = ((const float4*)P_all)[t];
  float4 zb = ((const float4*)(z_bar + base))[t];
  float4 zh, zt;
  zh.x = (pg.x - eg * x.x) * ig; zh.y = (pg.y - eg * x.y) * ig;
  zh.z = (pg.z - eg * x.z) * ig; zh.w = (pg.w - eg * x.w) * ig;
  zt.x = (pa.x - ea * x.x) * ia; zt.y = (pa.y - ea * x.y) * ia;
  zt.z = (pa.z - ea * x.z) * ia; zt.w = (pa.w - ea * x.w) * ia;
  *(ushort4*)(zhat_bf + base + t * 4) = make_ushort4(f2bf(zh.x), f2bf(zh.y), f2bf(zh.z), f2bf(zh.w));
  *(ushort4*)(ztum_bf + base + t * 4) = make_ushort4(f2bf(zt.x), f2bf(zt.y), f2bf(zt.z), f2bf(zt.w));
  float nz2 = x.x*x.x + x.y*x.y + x.z*x.z + x.w*x.w;
  float nh2 = zh.x*zh.x + zh.y*zh.y + zh.z*zh.z + zh.w*zh.w;
  float dzh = x.x*zh.x + x.y*zh.y + x.z*zh.z + x.w*zh.w;
  float nb2 = zb.x*zb.x + zb.y*zb.y + zb.z*zb.z + zb.w*zb.w;
  float dzb = x.x*zb.x + x.y*zb.y + x.z*zb.z + x.w*zb.w;
  float s_nz2 = block_sum(nz2, sb);
  float s_nh2 = block_sum(nh2, sb);
  float s_dzh = block_sum(dzh, sb);
  float s_nb2 = block_sum(nb2, sb);
  float s_dzb = block_sum(dzb, sb);
  if (t == 0){
    float nz = sqrtf(s_nz2);
    nz_arr[i] = nz;
    float denA = fmaxf(nz, 1e-8f) * fmaxf(sqrtf(s_nh2), 1e-8f);
    float denB = fmaxf(nz, 1e-8f) * fmaxf(sqrtf(s_nb2), 1e-8f);
    atomicAdd(&accum[0], (1.f - s_dzh / denA) + (1.f - s_dzb / denB));
  }
}

// per-row: dt = z.pt, ||pt||, dpn = z.(C+w), ||C+w||, g = z.w; hinge accumulation
__global__ __launch_bounds__(256) void k_rowred2(const float* __restrict__ z_all,
        const float* __restrict__ PT, const float* __restrict__ C,
        const float* __restrict__ w_norm, const float* __restrict__ nz_arr,
        float* __restrict__ dt_arr, float* __restrict__ g_arr, float* __restrict__ accum){
  __shared__ float sb[4];
  int i = blockIdx.x, t = threadIdx.x;
  size_t base = (size_t)i * D;
  float4 x  = ((const float4*)(z_all + base))[t];
  float4 pt = ((const float4*)(PT + base))[t];
  float4 c  = ((const float4*)(C + base))[t];
  float4 wv = ((const float4*)w_norm)[t];
  float4 pn = make_float4(c.x + wv.x, c.y + wv.y, c.z + wv.z, c.w + wv.w);
  float dt   = x.x*pt.x + x.y*pt.y + x.z*pt.z + x.w*pt.w;
  float npt2 = pt.x*pt.x + pt.y*pt.y + pt.z*pt.z + pt.w*pt.w;
  float dpn  = x.x*pn.x + x.y*pn.y + x.z*pn.z + x.w*pn.w;
  float npn2 = pn.x*pn.x + pn.y*pn.y + pn.z*pn.z + pn.w*pn.w;
  float gg   = x.x*wv.x + x.y*wv.y + x.z*wv.z + x.w*wv.w;
  float s_dt   = block_sum(dt, sb);
  float s_npt2 = block_sum(npt2, sb);
  float s_dpn  = block_sum(dpn, sb);
  float s_npn2 = block_sum(npn2, sb);
  float s_g    = block_sum(gg, sb);
  if (t == 0){
    dt_arr[i] = s_dt; g_arr[i] = s_g;
    float nz = fmaxf(nz_arr[i], 1e-8f);
    float ct = s_dt  / (nz * fmaxf(sqrtf(s_npt2), 1e-8f));
    float cn = s_dpn / (nz * fmaxf(sqrtf(s_npn2), 1e-8f));
    atomicAdd(&accum[1], fmaxf(0.f, 1.f - (ct - cn)));
  }
}

__global__ __launch_bounds__(256) void k_combine(const float2* __restrict__ partials,
        const float* __restrict__ diagM, const float* __restrict__ dt,
        const float* __restrict__ g, float* __restrict__ accum){
  __shared__ float sb[4];
  int i = blockIdx.x * 256 + threadIdx.x;
  float m = -1e30f, S = 0.f;
  for (int c = 0; c < NCHUNK; ++c){
    float2 p = partials[(size_t)c * BTOT + i];
    float nm = fmaxf(m, p.x);
    S = S * __expf(m - nm) + p.y * __expf(p.x - nm);
    m = nm;
  }
  float vold = diagM[i];
  float vnew = dt[i] - g[i];
  float nm = fmaxf(m, vnew);
  float S2 = S * __expf(m - nm) - __expf(vold - nm) + __expf(vnew - nm);
  float lse = g[i] + nm + logf(S2);
  float contrib = lse - dt[i];
  float tot = block_sum(contrib, sb);
  if (threadIdx.x == 0) atomicAdd(&accum[2], tot);
}

__global__ void k_final(const float* __restrict__ accum, float* __restrict__ out){
  out[0] = accum[2] / (float)BTOT;
  out[1] = (accum[0] + accum[1]) / (float)BTOT;
}

// ---------------- launch ----------------
extern "C" void kernel_launch(void* const* d_in, const int* in_sizes, int n_in,
                              void* d_out, int out_size, void* d_ws, size_t ws_size,
                              hipStream_t stream){
  const float* z_low    = (const float*)d_in[0];
  const float* z_high   = (const float*)d_in[1];
  const float* z_bar    = (const float*)d_in[2];
  const float* z_normal = (const float*)d_in[3];
  const float* Wa1      = (const float*)d_in[4];
  const float* ba1      = (const float*)d_in[5];
  const float* Wa2      = (const float*)d_in[6];
  const float* ba2      = (const float*)d_in[7];   // dropped: softmax shift-invariant
  const float* W0       = (const float*)d_in[8];
  const float* b0       = (const float*)d_in[9];
  const float* W1       = (const float*)d_in[10];
  const float* b1       = (const float*)d_in[11];
  float* ws = (float*)d_ws;
  unsigned short* bw = (unsigned short*)(ws + BF_BASE_F);
  float* out = (float*)d_out;
  (void)ba2;

  k_prep<<<dim3(BTOT, 1, 3), dim3(256), 0, stream>>>(z_low, z_high, z_normal, z_bar,
      ws + OFF_ZALL, bw + BF_ZALLN, bw + BF_ZBAR);
  k_tconv3<<<dim3(32, 32, 3), dim3(256), 0, stream>>>(W0, W1, Wa1,
      bw + BF_W0T, bw + BF_W1T, bw + BF_WA1T);
  k_zero13<<<dim3(53), dim3(256), 0, stream>>>(ws);

  // scores over [z_all ; z_normal] in one call (M = 8192)
  k_scores_bf<<<dim3(2, 64), dim3(256), 0, stream>>>(bw + BF_ZALLN, bw + BF_WA1T,
      ba1, Wa2, ws + OFF_SALL);

  k_stats<<<dim3(1), dim3(256), 0, stream>>>(ws + OFF_SALL, ws + OFF_SNORM,
      ws + OFF_EGRP, ws + OFF_ENORM, ws + OFF_STATS);

  k_pvec<<<dim3(1, 256, 3), dim3(256), 0, stream>>>(ws + OFF_ZALL, z_normal,
      ws + OFF_EGRP, ws + OFF_ENORM, ws + OFF_PLOW);

  k_smallvec<<<dim3(4), dim3(256), 0, stream>>>(ws + OFF_PLOW, ws + OFF_STATS,
      b0, b1, ws + OFF_PALL, ws + OFF_ZNV, ws + OFF_BIASC);

  k_wnorm<<<dim3(4, 8), dim3(256), 0, stream>>>(ws + OFF_ZNV, W0, ws + OFF_WNORM);

  k_zhat<<<dim3(BTOT), dim3(256), 0, stream>>>(ws + OFF_ZALL, z_bar,
      ws + OFF_EGRP, ws + OFF_STATS,
      ws + OFF_PLOW, ws + OFF_PHIGH, ws + OFF_PALL,
      bw + BF_ZHAT, bw + BF_ZTUM, ws + OFF_NZ, ws + OFF_ACC);

  // C = z_hat @ W0 + z_bar @ W1 + biasC ; PT = C + z_tumor @ W0  (one kernel)
  k_gemm_cpt<<<dim3(8, 32), dim3(256), 0, stream>>>(bw + BF_ZHAT, bw + BF_ZBAR,
      bw + BF_ZTUM, bw + BF_W0T, bw + BF_W1T, ws + OFF_BIASC,
      ws + OFF_C, bw + BF_C, ws + OFF_PT);

  k_rowred2<<<dim3(BTOT), dim3(256), 0, stream>>>(ws + OFF_ZALL, ws + OFF_PT,
      ws + OFF_C, ws + OFF_WNORM, ws + OFF_NZ, ws + OFF_DT, ws + OFF_G, ws + OFF_ACC);

  k_gemm_lse<<<dim3(32, 32), dim3(256), 0, stream>>>(bw + BF_ZALLN, bw + BF_C,
      (float2*)(ws + OFF_PART), ws + OFF_DIAG);

  k_combine<<<dim3(16), dim3(256), 0, stream>>>((const float2*)(ws + OFF_PART),
      ws + OFF_DIAG, ws + OFF_DT, ws + OFF_G, ws + OFF_ACC);

  k_final<<<dim3(1), dim3(1), 0, stream>>>(ws + OFF_ACC, out);
}